// Round 6
// baseline (524.633 us; speedup 1.0000x reference)
//
#include <hip/hip_runtime.h>
#include <math.h>

// N=5, B=8, C=256, H*W=1024
#define NN 5
#define CC 256
#define SSP 1024
#define BB 8
#define THRESHV 0.3f

typedef __attribute__((ext_vector_type(8))) short short8;   // 8 bf16 = one MFMA A/B frag
typedef __attribute__((ext_vector_type(4))) float f32x4;    // MFMA 16x16 accumulator

// ---------------- ws layout (bytes) ----------------
// X split planes, k-minor: [(j*8+b)*3+sp][s:1024][k:256] bf16
#define XW_OFF   0ull
#define XW_PLANE ((size_t)SSP * CC * 2)                 // 524288
#define XW_SIZE  ((size_t)NN * BB * 3 * XW_PLANE)       // 62,914,560
// A = W1+W2 split planes, k-minor: [i*3+sp][o:256][k:256]
#define AW_OFF   XW_SIZE
#define AW_PLANE ((size_t)CC * CC * 2)                  // 131072
#define AW_SIZE  ((size_t)NN * 3 * AW_PLANE)            // 1,966,080
#define W2_OFF   (AW_OFF + AW_SIZE)
#define WS_NEED  (W2_OFF + AW_SIZE)                     // ~63.8 MiB

// ---- exact 3-way bf16 split (Dekker-style; residuals exact in fp32) ----
static __device__ __forceinline__ unsigned short f2bf(float f) {
    unsigned int u = __builtin_bit_cast(unsigned int, f);
    u = u + 0x7fffu + ((u >> 16) & 1u);          // RNE to bf16
    return (unsigned short)(u >> 16);
}
static __device__ __forceinline__ float bf2f(unsigned short h) {
    unsigned int u = ((unsigned int)h) << 16;
    return __builtin_bit_cast(float, u);
}
static __device__ __forceinline__ void split3(float a, unsigned short& h,
                                              unsigned short& m, unsigned short& l) {
    h = f2bf(a); float r1 = a - bf2f(h);
    m = f2bf(r1); float r2 = r1 - bf2f(m);
    l = f2bf(r2);
}
static __device__ __forceinline__ f32x4 MF(short8 a, short8 b, f32x4 c) {
    return __builtin_amdgcn_mfma_f32_16x16x32_bf16(a, b, c, 0, 0, 0);
}

// async global->LDS, 16B per lane (used by the fallback only)
#define GLD16(gp, lp) __builtin_amdgcn_global_load_lds(                          \
        (const __attribute__((address_space(1))) unsigned int*)(gp),             \
        (__attribute__((address_space(3))) unsigned int*)(lp), 16, 0, 0)

// ================= pre-pass: split weights =================
__global__ __launch_bounds__(256)
void prep_w(const float* __restrict__ w, unsigned char* __restrict__ ws) {
    const int id = blockIdx.x * 256 + threadIdx.x;   // 40960 = 5*256*32
    const int i  = id >> 13;
    const int o  = (id >> 5) & 255;
    const int ko = id & 31;                          // k-oct
    const float* gw = w + (size_t)(i * CC + o) * (2 * CC) + ko * 8;
    float av[8], wv[8];
    #pragma unroll
    for (int kk = 0; kk < 8; kk++) {
        wv[kk] = gw[CC + kk];
        av[kk] = gw[kk] + wv[kk];
    }
    unsigned short h[8], m[8], l[8];
    short8 H, M, L;
    #pragma unroll
    for (int kk = 0; kk < 8; kk++) split3(av[kk], h[kk], m[kk], l[kk]);
    #pragma unroll
    for (int kk = 0; kk < 8; kk++) { H[kk] = (short)h[kk]; M[kk] = (short)m[kk]; L[kk] = (short)l[kk]; }
    {
        unsigned char* p = ws + AW_OFF + (size_t)((i * 3) * CC + o) * 512 + ko * 16;
        *(short8*)(p)                = H;
        *(short8*)(p + CC * 512)     = M;
        *(short8*)(p + 2 * CC * 512) = L;
    }
    #pragma unroll
    for (int kk = 0; kk < 8; kk++) split3(wv[kk], h[kk], m[kk], l[kk]);
    #pragma unroll
    for (int kk = 0; kk < 8; kk++) { H[kk] = (short)h[kk]; M[kk] = (short)m[kk]; L[kk] = (short)l[kk]; }
    {
        unsigned char* p = ws + W2_OFF + (size_t)((i * 3) * CC + o) * 512 + ko * 16;
        *(short8*)(p)                = H;
        *(short8*)(p + CC * 512)     = M;
        *(short8*)(p + 2 * CC * 512) = L;
    }
}

// ================= pre-pass: split + transpose x (1280 blocks) ======
__global__ __launch_bounds__(256)
void prep_x(const float* __restrict__ x, unsigned char* __restrict__ ws) {
    const int blk = blockIdx.x;          // 1280 = 40 jb * 8 kc * 4 r
    const int r   = blk & 3;
    const int kc  = (blk >> 2) & 7;
    const int jb  = blk >> 5;            // j*8+b
    const int k0  = kc * 32;
    const int s   = threadIdx.x + 256 * r;
    const float* gx = x + ((size_t)jb * CC + k0) * SSP + s;
    unsigned char* w0 = ws + XW_OFF + (size_t)(jb * 3) * XW_PLANE
                      + (size_t)s * 512 + (size_t)k0 * 2;
    #pragma unroll
    for (int oct = 0; oct < 4; oct++) {
        float v[8];
        #pragma unroll
        for (int kk = 0; kk < 8; kk++) v[kk] = gx[(size_t)(oct * 8 + kk) * SSP];
        unsigned short h[8], m[8], l[8];
        #pragma unroll
        for (int kk = 0; kk < 8; kk++) split3(v[kk], h[kk], m[kk], l[kk]);
        short8 H, M, L;
        #pragma unroll
        for (int kk = 0; kk < 8; kk++) { H[kk] = (short)h[kk]; M[kk] = (short)m[kk]; L[kk] = (short)l[kk]; }
        *(short8*)(w0 + oct * 16)                 = H;
        *(short8*)(w0 + XW_PLANE + oct * 16)      = M;
        *(short8*)(w0 + 2 * XW_PLANE + oct * 16)  = L;
    }
}

// ================= main: barrier-free all-register kernel =================
// Rationale (R3/R4/R5 lesson): every barrier/wait scheme lost to R2; the per-wave
// operand footprint (45 KB/chunk) is small and wave-private, so drop LDS and
// __syncthreads entirely. Each wave loads its own fragments global->reg,
// software-pipelined one j ahead via two NAMED frag sets (A/B; k-loop unrolled
// x2 so buffer parity is compile-time -> no runtime reg indexing). The 2
// waves/SIMD drift freely; one wave's L2 latency hides under the other's MFMAs.
// af(k+1) reload sits between the last Y-block and the last U-block (U doesn't
// use af). Product set + accumulation order identical to R2 -> bit-exact.
__global__ __launch_bounds__(256, 2)
void fub_reg(const float* __restrict__ x, const float* __restrict__ bias,
             const unsigned char* __restrict__ ws, float* __restrict__ out)
{
    const int tid  = threadIdx.x;
    const int b    = blockIdx.z;
    const int o0   = blockIdx.y * 32;
    const int s0   = blockIdx.x * 32;
    const int lane = tid & 63;
    const int w    = tid >> 6;            // wave 0..3 -> tile quarter
    const int oh   = w >> 1, sh = w & 1;
    const int qd   = lane >> 4;
    const int m_   = lane & 15;
    const int ar   = 16 * oh + m_;        // o row for A/W2 frags
    const int xr   = 16 * sh + m_;        // s row for X frags

    // per-lane base byte-offsets into ws
    const unsigned vX  = (unsigned)(b * 3 * XW_PLANE)
                       + (unsigned)((s0 + xr) * 512 + qd * 16);
    const unsigned vAW = (unsigned)AW_OFF + (unsigned)((o0 + ar) * 512) + (unsigned)(qd * 16);
    const unsigned vW2 = (unsigned)W2_OFF + (unsigned)((o0 + ar) * 512) + (unsigned)(qd * 16);

#define LD8(off)      (*(const short8*)(ws + (off)))
#define XOFF(j, sp, ko)  (vX  + (unsigned)((j) * 24 + (sp)) * (unsigned)XW_PLANE + (ko))
#define WOFF(j, sp, ko)  (vW2 + (unsigned)(((j) * 3 + (sp)) * AW_PLANE) + (ko))
#define AOFF(i, sp, ko)  (vAW + (unsigned)(((i) * 3 + (sp)) * AW_PLANE) + (ko))

    f32x4 accY[NN][NN];
    f32x4 accU[NN];
    #pragma unroll
    for (int ii = 0; ii < NN; ii++) {
        accU[ii] = (f32x4){0.f, 0.f, 0.f, 0.f};
        #pragma unroll
        for (int j = 0; j < NN; j++) accY[ii][j] = (f32x4){0.f, 0.f, 0.f, 0.f};
    }

    short8 af[NN][3];                                   // weight frags (60 VGPR)
    short8 xa0, xa1, xa2, wa0, wa1, wa2;                // frag set A
    short8 xb0, xb1, xb2, wb0, wb1, wb2;                // frag set B

#define LOADAF(ko)                                                              \
    { _Pragma("unroll")                                                         \
      for (int ii = 0; ii < NN; ii++) {                                         \
          af[ii][0] = LD8(AOFF(ii, 0, ko));                                     \
          af[ii][1] = LD8(AOFF(ii, 1, ko));                                     \
          af[ii][2] = LD8(AOFF(ii, 2, ko));                                     \
      } }
#define LOADA(j, ko)                                                            \
    { xa0 = LD8(XOFF(j, 0, ko)); xa1 = LD8(XOFF(j, 1, ko));                     \
      xa2 = LD8(XOFF(j, 2, ko));                                                \
      wa0 = LD8(WOFF(j, 0, ko)); wa1 = LD8(WOFF(j, 1, ko));                     \
      wa2 = LD8(WOFF(j, 2, ko)); }
#define LOADB(j, ko)                                                            \
    { xb0 = LD8(XOFF(j, 0, ko)); xb1 = LD8(XOFF(j, 1, ko));                     \
      xb2 = LD8(XOFF(j, 2, ko));                                                \
      wb0 = LD8(WOFF(j, 0, ko)); wb1 = LD8(WOFF(j, 1, ko));                     \
      wb2 = LD8(WOFF(j, 2, ko)); }

#define CY(j, X0, X1, X2)                                                       \
    { _Pragma("unroll")                                                         \
      for (int ii = 0; ii < NN; ii++) {                                         \
          f32x4 c = accY[ii][j];                                                \
          c = MF(af[ii][0], X0, c);                                             \
          c = MF(af[ii][0], X1, c);                                             \
          c = MF(af[ii][1], X0, c);                                             \
          c = MF(af[ii][1], X1, c);                                             \
          c = MF(af[ii][0], X2, c);                                             \
          c = MF(af[ii][2], X0, c);                                             \
          accY[ii][j] = c;                                                      \
      } }
#define CU(j, X0, X1, X2, W0, W1, W2v)                                          \
    { f32x4 u = accU[j];                                                        \
      u = MF(W0, X0, u);                                                        \
      u = MF(W0, X1, u);                                                        \
      u = MF(W1, X0, u);                                                        \
      u = MF(W1, X1, u);                                                        \
      u = MF(W0, X2, u);                                                        \
      u = MF(W2v, X0, u);                                                       \
      accU[j] = u; }

    // chunk with j=0 frags in set A; ends with set B holding j=0 of chunk k+1
#define CHUNK_A(ko, koN)                                                        \
    {                                                                           \
        LOADB(1, ko); CY(0, xa0, xa1, xa2); CU(0, xa0, xa1, xa2, wa0, wa1, wa2);\
        LOADA(2, ko); CY(1, xb0, xb1, xb2); CU(1, xb0, xb1, xb2, wb0, wb1, wb2);\
        LOADB(3, ko); CY(2, xa0, xa1, xa2); CU(2, xa0, xa1, xa2, wa0, wa1, wa2);\
        LOADA(4, ko); CY(3, xb0, xb1, xb2); CU(3, xb0, xb1, xb2, wb0, wb1, wb2);\
        LOADB(0, koN);                                                          \
        CY(4, xa0, xa1, xa2);                                                   \
        LOADAF(koN);                                                            \
        CU(4, xa0, xa1, xa2, wa0, wa1, wa2);                                    \
    }
    // chunk with j=0 frags in set B; LAST=1 suppresses next-chunk prefetch
#define CHUNK_B(ko, koN, LAST)                                                  \
    {                                                                           \
        LOADA(1, ko); CY(0, xb0, xb1, xb2); CU(0, xb0, xb1, xb2, wb0, wb1, wb2);\
        LOADB(2, ko); CY(1, xa0, xa1, xa2); CU(1, xa0, xa1, xa2, wa0, wa1, wa2);\
        LOADA(3, ko); CY(2, xb0, xb1, xb2); CU(2, xb0, xb1, xb2, wb0, wb1, wb2);\
        LOADB(4, ko); CY(3, xa0, xa1, xa2); CU(3, xa0, xa1, xa2, wa0, wa1, wa2);\
        if (!(LAST)) { LOADA(0, koN); }                                         \
        CY(4, xb0, xb1, xb2);                                                   \
        if (!(LAST)) { LOADAF(koN); }                                           \
        CU(4, xb0, xb1, xb2, wb0, wb1, wb2);                                    \
    }

    // prologue: af(0) + j=0 frags of chunk 0 into set A
    LOADAF(0u);
    LOADA(0, 0u);

    #pragma unroll 1
    for (int kk = 0; kk < 4; kk++) {
        const unsigned ko0 = (unsigned)(kk * 128);        // chunk 2kk   (k*64)
        const unsigned ko1 = ko0 + 64u;                   // chunk 2kk+1
        const unsigned ko2 = ko0 + 128u;                  // chunk 2kk+2
        CHUNK_A(ko0, ko1)
        CHUNK_B(ko1, ko2, kk == 3)
    }

    // ---------------- epilogue (C/D: col=lane&15, row=qd*4+reg) ----------------
    const int sg  = s0 + 16 * sh + m_;
    const int og0 = o0 + 16 * oh + 4 * qd;

    float xe[NN][4];
    #pragma unroll
    for (int j = 0; j < NN; j++) {
        const float* px = x + (size_t)((j * BB + b) * CC + og0) * SSP + sg;
        #pragma unroll
        for (int r = 0; r < 4; r++) xe[j][r] = px[r * SSP];
    }

    #pragma unroll
    for (int ii = 0; ii < NN; ii++) {
        #pragma unroll
        for (int r = 0; r < 4; r++) {
            const float uu = accU[ii][r] + bias[ii * CC + og0 + r];
            float e[NN]; float mx = 0.f;
            #pragma unroll
            for (int j = 0; j < NN; j++) {
                float d = fabsf(xe[j][r] - (accY[ii][j][r] + uu));
                d = (d > THRESHV) ? d : 0.f;
                e[j] = d; mx = fmaxf(mx, d);
            }
            float sum = 0.f, hv = 0.f;
            #pragma unroll
            for (int j = 0; j < NN; j++) {
                const float p = __expf(e[j] - mx);
                sum += p; hv += p * xe[j][r];
            }
            out[(size_t)((ii * BB + b) * CC + og0 + r) * SSP + sg] = hv / sum;
        }
    }
}

// ================= fallback (R2 kernel, self-splitting; known-good) ==========
static __device__ __forceinline__ void st4(unsigned short* p, unsigned short a,
                                           unsigned short b, unsigned short c, unsigned short d) {
    ushort4 v; v.x = a; v.y = b; v.z = c; v.w = d;
    *(ushort4*)p = v;
}
#define XB 15360
__global__ __launch_bounds__(512, 2)
void fub_mfma(const float* __restrict__ x, const float* __restrict__ w,
              const float* __restrict__ bias, float* __restrict__ out)
{
    __shared__ unsigned short S[30720];
    const int tid = threadIdx.x;
    const int b = blockIdx.z, o0 = blockIdx.y * 32, s0 = blockIdx.x * 32;
    const int lane = tid & 63, wv = tid >> 6;
    const int q = wv & 3, oh = q >> 1, sh = q & 1, iset = wv >> 2, qd = lane >> 4;
    const int sub = tid >> 8, t = tid & 255;
    const int wo = t >> 3, wkg = t & 7, xs = t & 31, xkq = t >> 5;
    const int wbase = wo * 32 + (((wkg >> 1) ^ ((wo >> 1) & 3)) << 3) + ((wkg & 1) << 2);
    const int xbase = xs * 32 + (((xkq >> 1) ^ ((xs >> 1) & 3)) << 3) + ((xkq & 1) << 2);
    const int ar = 16 * oh + (lane & 15), xr = 16 * sh + (lane & 15);
    const int asw8 = ((qd ^ ((ar >> 1) & 3)) << 3), xsw8 = ((qd ^ ((xr >> 1) & 3)) << 3);
    const int arow32 = ar * 32, xrow32 = xr * 32;
    f32x4 accY[3][5]; f32x4 accU[3];
    #pragma unroll
    for (int ii = 0; ii < 3; ii++) {
        accU[ii] = (f32x4){0.f, 0.f, 0.f, 0.f};
        #pragma unroll
        for (int j = 0; j < NN; j++) accY[ii][j] = (f32x4){0.f, 0.f, 0.f, 0.f};
    }
    float w2sav[3][4];
    #pragma unroll 1
    for (int k0 = 0; k0 < CC; k0 += 32) {
        if (k0) __syncthreads();
        #pragma unroll
        for (int rep = 0; rep < 3; rep++) {
            const int i = rep * 2 + sub;
            if (i < NN) {
                const float* gw = w + (size_t)(i * CC + o0 + wo) * (2 * CC) + k0 + wkg * 4;
                const float4 w1 = *(const float4*)gw;
                const float4 w2 = *(const float4*)(gw + CC);
                w2sav[rep][0] = w2.x; w2sav[rep][1] = w2.y; w2sav[rep][2] = w2.z; w2sav[rep][3] = w2.w;
                float av[4] = {w1.x + w2.x, w1.y + w2.y, w1.z + w2.z, w1.w + w2.w};
                unsigned short h[4], m[4], l[4];
                #pragma unroll
                for (int r = 0; r < 4; r++) split3(av[r], h[r], m[r], l[r]);
                unsigned short* p = &S[i * 3 * 1024 + wbase];
                st4(p, h[0], h[1], h[2], h[3]); st4(p + 1024, m[0], m[1], m[2], m[3]); st4(p + 2048, l[0], l[1], l[2], l[3]);
            }
        }
        #pragma unroll
        for (int rep = 0; rep < 3; rep++) {
            const int j = rep * 2 + sub;
            if (j < NN) {
                const float* gx = x + (size_t)((j * BB + b) * CC + k0 + xkq * 4) * SSP + s0 + xs;
                float v[4] = {gx[0], gx[SSP], gx[2 * SSP], gx[3 * SSP]};
                unsigned short h[4], m[4], l[4];
                #pragma unroll
                for (int r = 0; r < 4; r++) split3(v[r], h[r], m[r], l[r]);
                unsigned short* p = &S[XB + j * 3 * 1024 + xbase];
                st4(p, h[0], h[1], h[2], h[3]); st4(p + 1024, m[0], m[1], m[2], m[3]); st4(p + 2048, l[0], l[1], l[2], l[3]);
            }
        }
        __syncthreads();
        short8 xf[NN][3];
        #pragma unroll
        for (int j = 0; j < NN; j++)
            #pragma unroll
            for (int sp = 0; sp < 3; sp++)
                xf[j][sp] = *(const short8*)&S[XB + (j * 3 + sp) * 1024 + xrow32 + xsw8];
#define YPL(IB_, NI_)                                                           \
        {                                                                       \
            _Pragma("unroll")                                                   \
            for (int ii = 0; ii < NI_; ii++) {                                  \
                const int i = IB_ + ii;                                         \
                const unsigned short* ap = &S[i * 3 * 1024 + arow32 + asw8];    \
                const short8 ah = *(const short8*)(ap);                         \
                const short8 am = *(const short8*)(ap + 1024);                  \
                const short8 al = *(const short8*)(ap + 2048);                  \
                _Pragma("unroll")                                               \
                for (int j = 0; j < NN; j++) {                                  \
                    f32x4 c = accY[ii][j];                                      \
                    c = MF(ah, xf[j][0], c); c = MF(ah, xf[j][1], c);           \
                    c = MF(am, xf[j][0], c); c = MF(am, xf[j][1], c);           \
                    c = MF(ah, xf[j][2], c); c = MF(al, xf[j][0], c);           \
                    accY[ii][j] = c;                                            \
                }                                                               \
            }                                                                   \
        }
        if (iset == 0) { YPL(0, 2) } else { YPL(2, 3) }
        __syncthreads();
        #pragma unroll
        for (int rep = 0; rep < 3; rep++) {
            const int i = rep * 2 + sub;
            if (i < NN) {
                unsigned short h[4], m[4], l[4];
                #pragma unroll
                for (int r = 0; r < 4; r++) split3(w2sav[rep][r], h[r], m[r], l[r]);
                unsigned short* p = &S[i * 3 * 1024 + wbase];
                st4(p, h[0], h[1], h[2], h[3]); st4(p + 1024, m[0], m[1], m[2], m[3]); st4(p + 2048, l[0], l[1], l[2], l[3]);
            }
        }
        __syncthreads();
#define UPL(IB_, NI_)                                                           \
        {                                                                       \
            _Pragma("unroll")                                                   \
            for (int ii = 0; ii < NI_; ii++) {                                  \
                const int i = IB_ + ii;                                         \
                const unsigned short* wp = &S[i * 3 * 1024 + arow32 + asw8];    \
                const short8 wh = *(const short8*)(wp);                         \
                const short8 wm = *(const short8*)(wp + 1024);                  \
                const short8 wl = *(const short8*)(wp + 2048);                  \
                f32x4 u = accU[ii];                                             \
                u = MF(wh, xf[i][0], u); u = MF(wh, xf[i][1], u);               \
                u = MF(wm, xf[i][0], u); u = MF(wm, xf[i][1], u);               \
                u = MF(wh, xf[i][2], u); u = MF(wl, xf[i][0], u);               \
                accU[ii] = u;                                                   \
            }                                                                   \
        }
        if (iset == 0) { UPL(0, 2) } else { UPL(2, 3) }
    }
    const int sg = s0 + 16 * sh + (lane & 15);
    const int og0 = o0 + 16 * oh + 4 * qd;
    float xe[NN][4];
    #pragma unroll
    for (int j = 0; j < NN; j++) {
        const float* px = x + (size_t)((j * BB + b) * CC + og0) * SSP + sg;
        #pragma unroll
        for (int r = 0; r < 4; r++) xe[j][r] = px[r * SSP];
    }
#define EPI(IB_, NI_)                                                           \
    {                                                                           \
        _Pragma("unroll")                                                       \
        for (int ii = 0; ii < NI_; ii++) {                                      \
            const int i = IB_ + ii;                                             \
            _Pragma("unroll")                                                   \
            for (int r = 0; r < 4; r++) {                                       \
                const float uu = accU[ii][r] + bias[i * CC + og0 + r];          \
                float e[NN]; float mx = 0.f;                                    \
                _Pragma("unroll")                                               \
                for (int j = 0; j < NN; j++) {                                  \
                    float d = fabsf(xe[j][r] - (accY[ii][j][r] + uu));          \
                    d = (d > THRESHV) ? d : 0.f;                                \
                    e[j] = d; mx = fmaxf(mx, d);                                \
                }                                                               \
                float sum = 0.f, hv = 0.f;                                      \
                _Pragma("unroll")                                               \
                for (int j = 0; j < NN; j++) {                                  \
                    const float p = __expf(e[j] - mx);                          \
                    sum += p; hv += p * xe[j][r];                               \
                }                                                               \
                out[(size_t)((i * BB + b) * CC + og0 + r) * SSP + sg] = hv / sum; \
            }                                                                   \
        }                                                                       \
    }
    if (iset == 0) { EPI(0, 2) } else { EPI(2, 3) }
}

extern "C" void kernel_launch(void* const* d_in, const int* in_sizes, int n_in,
                              void* d_out, int out_size, void* d_ws, size_t ws_size,
                              hipStream_t stream) {
    const float* x      = (const float*)d_in[0];
    const float* conv_w = (const float*)d_in[1];
    const float* conv_b = (const float*)d_in[2];
    float* out = (float*)d_out;

    if (ws_size >= WS_NEED) {
        unsigned char* ws = (unsigned char*)d_ws;
        prep_w<<<160, 256, 0, stream>>>(conv_w, ws);
        prep_x<<<1280, 256, 0, stream>>>(x, ws);
        dim3 grid(SSP / 32, CC / 32, BB);   // 2048 blocks, 4 independent waves
        fub_reg<<<grid, 256, 0, stream>>>(x, conv_b, ws, out);
    } else {
        fub_mfma<<<dim3(SSP / 32, CC / 32, BB), 512, 0, stream>>>(x, conv_w, conv_b, out);
    }
}

// Round 7
// 298.366 us; speedup vs baseline: 1.7584x; 1.7584x over previous
//
#include <hip/hip_runtime.h>
#include <math.h>

// N=5, B=8, C=256, H*W=1024
#define NN 5
#define CC 256
#define SSP 1024
#define BB 8
#define THRESHV 0.3f

typedef __attribute__((ext_vector_type(8))) short short8;   // 8 bf16 = one MFMA A/B frag
typedef __attribute__((ext_vector_type(4))) float f32x4;    // MFMA 16x16 accumulator

// ---------------- ws layout (bytes) ----------------
// X split planes, k-minor: [(j*8+b)*3+sp][s:1024][k:256] bf16
#define XW_OFF   0ull
#define XW_PLANE ((size_t)SSP * CC * 2)                 // 524288
#define XW_SIZE  ((size_t)NN * BB * 3 * XW_PLANE)       // 62,914,560
// A = W1+W2 split planes, k-minor: [i*3+sp][o:256][k:256]
#define AW_OFF   XW_SIZE
#define AW_PLANE ((size_t)CC * CC * 2)                  // 131072
#define AW_SIZE  ((size_t)NN * 3 * AW_PLANE)            // 1,966,080
#define W2_OFF   (AW_OFF + AW_SIZE)
#define WS_NEED  (W2_OFF + AW_SIZE)                     // ~63.8 MiB

// ---- exact 3-way bf16 split (Dekker-style; residuals exact in fp32) ----
static __device__ __forceinline__ unsigned short f2bf(float f) {
    unsigned int u = __builtin_bit_cast(unsigned int, f);
    u = u + 0x7fffu + ((u >> 16) & 1u);          // RNE to bf16
    return (unsigned short)(u >> 16);
}
static __device__ __forceinline__ float bf2f(unsigned short h) {
    unsigned int u = ((unsigned int)h) << 16;
    return __builtin_bit_cast(float, u);
}
static __device__ __forceinline__ void split3(float a, unsigned short& h,
                                              unsigned short& m, unsigned short& l) {
    h = f2bf(a); float r1 = a - bf2f(h);
    m = f2bf(r1); float r2 = r1 - bf2f(m);
    l = f2bf(r2);
}
static __device__ __forceinline__ f32x4 MF(short8 a, short8 b, f32x4 c) {
    return __builtin_amdgcn_mfma_f32_16x16x32_bf16(a, b, c, 0, 0, 0);
}

// async global->LDS, 16B per lane; LDS dest = uniform base + lane*16
#define GLD16(gp, lp) __builtin_amdgcn_global_load_lds(                          \
        (const __attribute__((address_space(1))) unsigned int*)(gp),             \
        (__attribute__((address_space(3))) unsigned int*)(lp), 16, 0, 0)

// ================= merged pre-pass =================
// Blocks 0..319  : X split+transpose via LDS (40 jb * 8 kc).
//   - reads coalesced (256B/instr), split3, staged in swizzled LDS tile,
//   - writes 64B-contiguous bursts (4 lanes x 16B per s-row) -- the old
//     per-thread version wrote 16B at 512B stride (~4x write amplification,
//     ~80-100us of the wall clock).
// Blocks 320..479: weight split (identical math to the old prep_w).
// LDS tile: 3 planes x 256 s-rows x PXS(=40) shorts (pad -> 16B-aligned b128
// reads, stride 80B). Unit swizzle po = o ^ (s&3) ^ ((s>>3)&3) keeps both the
// b32 writes and b128 reads <=2-way bank-conflicted. Bit-identical output.
#define PXS 40
__global__ __launch_bounds__(256)
void prep_all(const float* __restrict__ x, const float* __restrict__ w,
              unsigned char* __restrict__ ws) {
    __shared__ unsigned short S[3 * 256 * PXS];      // 61440 B
    const int tid = threadIdx.x;

    if (blockIdx.x >= 320) {
        // ---------------- weight split (old prep_w, verbatim math) ----------
        const int id = (blockIdx.x - 320) * 256 + tid;   // 40960 = 5*256*32
        const int i  = id >> 13;
        const int o  = (id >> 5) & 255;
        const int ko = id & 31;                          // k-oct
        const float* gw = w + (size_t)(i * CC + o) * (2 * CC) + ko * 8;
        float av[8], wv[8];
        #pragma unroll
        for (int kk = 0; kk < 8; kk++) {
            wv[kk] = gw[CC + kk];
            av[kk] = gw[kk] + wv[kk];
        }
        unsigned short h[8], m[8], l[8];
        short8 H, M, L;
        #pragma unroll
        for (int kk = 0; kk < 8; kk++) split3(av[kk], h[kk], m[kk], l[kk]);
        #pragma unroll
        for (int kk = 0; kk < 8; kk++) { H[kk] = (short)h[kk]; M[kk] = (short)m[kk]; L[kk] = (short)l[kk]; }
        {
            unsigned char* p = ws + AW_OFF + (size_t)((i * 3) * CC + o) * 512 + ko * 16;
            *(short8*)(p)                = H;
            *(short8*)(p + CC * 512)     = M;
            *(short8*)(p + 2 * CC * 512) = L;
        }
        #pragma unroll
        for (int kk = 0; kk < 8; kk++) split3(wv[kk], h[kk], m[kk], l[kk]);
        #pragma unroll
        for (int kk = 0; kk < 8; kk++) { H[kk] = (short)h[kk]; M[kk] = (short)m[kk]; L[kk] = (short)l[kk]; }
        {
            unsigned char* p = ws + W2_OFF + (size_t)((i * 3) * CC + o) * 512 + ko * 16;
            *(short8*)(p)                = H;
            *(short8*)(p + CC * 512)     = M;
            *(short8*)(p + 2 * CC * 512) = L;
        }
        return;
    }

    // ---------------- X split + transpose (blocks 0..319) -------------------
    const int blk = blockIdx.x;          // 320 = 40 jb * 8 kc
    const int kc  = blk & 7;
    const int jb  = blk >> 3;            // j*8+b
    const int k0  = kc * 32;
    unsigned char* const pl0 = ws + XW_OFF + (size_t)(jb * 3) * XW_PLANE
                             + (size_t)(k0 * 2);
    const int swk = (tid & 3) ^ ((tid >> 3) & 3);     // writer-row swizzle key

    #pragma unroll 1
    for (int sc = 0; sc < 4; sc++) {
        if (sc) __syncthreads();
        const int s = sc * 256 + tid;
        const float* gx = x + ((size_t)jb * CC + k0) * SSP + s;
        // read coalesced, split, stage in LDS (row = this thread's s)
        #pragma unroll
        for (int kp = 0; kp < 16; kp++) {            // pairs of k
            const float v0 = gx[(size_t)(2 * kp) * SSP];
            const float v1 = gx[(size_t)(2 * kp + 1) * SSP];
            unsigned short h0, m0, l0, h1, m1, l1;
            split3(v0, h0, m0, l0);
            split3(v1, h1, m1, l1);
            const int po  = (kp >> 2) ^ swk;          // swizzled 16B unit
            const int idx = tid * PXS + po * 8 + (kp & 3) * 2;
            *(unsigned int*)&S[idx]             = (unsigned)h0 | ((unsigned)h1 << 16);
            *(unsigned int*)&S[idx + 256 * PXS] = (unsigned)m0 | ((unsigned)m1 << 16);
            *(unsigned int*)&S[idx + 512 * PXS] = (unsigned)l0 | ((unsigned)l1 << 16);
        }
        __syncthreads();
        // write out transposed: 4 lanes cover one 64B s-row segment
        #pragma unroll
        for (int sp = 0; sp < 3; sp++) {
            #pragma unroll
            for (int it = 0; it < 4; it++) {
                const int u   = it * 256 + tid;
                const int su  = u >> 2, ko = u & 3;
                const int pko = ko ^ (su & 3) ^ ((su >> 3) & 3);
                const short8 v = *(const short8*)&S[sp * 256 * PXS + su * PXS + pko * 8];
                *(short8*)(pl0 + (size_t)sp * XW_PLANE
                           + (size_t)(sc * 256 + su) * 512 + ko * 16) = v;
            }
        }
    }
}

// ================= main fused kernel (R2 structure, known-good 218us) ========
// LDS (61440 B): X planes [0..30719]: 15 planes (j*3+sp) x 2048B.
//                W2 planes [30720..61439]: 15 planes (i*3+sp) x 2048B.
// Both staged via global_load_lds with the bank swizzle carried in the per-lane
// DMA global address. A frags global->reg before the barrier (latency folds
// into the drain). 60 GLD16 slots per chunk = exactly 15 per wave.
template<int IB, int NI>
__global__ __launch_bounds__(256, 2)
void fub_main(const float* __restrict__ x, const float* __restrict__ bias,
              const unsigned char* __restrict__ ws, float* __restrict__ out)
{
    __shared__ unsigned char SB[61440];

    const int tid  = threadIdx.x;
    const int b    = blockIdx.z;
    const int o0   = blockIdx.y * 32;
    const int s0   = blockIdx.x * 32;
    const int lane = tid & 63;
    const int w    = tid >> 6;            // wave 0..3 -> tile quarter
    const int oh   = w >> 1, sh = w & 1;
    const int qd   = lane >> 4;
    const int m_   = lane & 15;
    const int ar   = 16 * oh + m_;        // o row for A/W2 frags
    const int xr   = 16 * sh + m_;        // s row for X frags

    // ---- DMA staging: 60 slots over 4 waves (15 each) ----
    // slots 0..29 : X planes (p = slot>>1 = j*3+sp), rows are s-rows
    // slots 30..59: W2 planes (p = (slot-30)>>1 = i*3+sp), rows are o-rows
    const int sbase = w * 15;
    unsigned gOff[15];
    #pragma unroll
    for (int t = 0; t < 15; t++) {
        const int slot = sbase + t;
        if (slot < 30) {
            const int p  = slot >> 1;              // plane 0..14 = j*3+sp
            const int jj = p / 3, sp = p - 3 * jj;
            const int u  = (slot & 1) * 64 + lane; // unit within plane
            const int sr = u >> 2;
            const int oc = (u & 3) ^ (sr & 3) ^ ((sr >> 2) & 3);
            gOff[t] = (unsigned)(((jj * BB + b) * 3 + sp) * XW_PLANE)
                    + (unsigned)((s0 + sr) * 512 + oc * 16);
        } else {
            const int sl = slot - 30;
            const int p  = sl >> 1;                // plane 0..14 = i*3+sp
            const int u  = (sl & 1) * 64 + lane;
            const int sr = u >> 2;                 // o-row within tile
            const int oc = (u & 3) ^ (sr & 3) ^ ((sr >> 2) & 3);
            gOff[t] = (unsigned)W2_OFF
                    + (unsigned)((p * CC + o0 + sr) * 512 + oc * 16);
        }
    }

    // ---- A frag per-lane base (k-minor planes) ----
    const unsigned vAW = (unsigned)AW_OFF + (unsigned)(o0 + ar) * 512u + (unsigned)qd * 16u;
    // X frag LDS byte offset (within plane, swizzled)
    const unsigned xb = (unsigned)(xr * 4 + (qd ^ (xr & 3) ^ ((xr >> 2) & 3))) * 16u;
    // W2 frag LDS byte offset (within plane, swizzled; o-row = ar)
    const unsigned wb = (unsigned)(ar * 4 + (qd ^ (ar & 3) ^ ((ar >> 2) & 3))) * 16u;

    f32x4 accY[NI][NN];
    f32x4 accU[NI];
    #pragma unroll
    for (int ii = 0; ii < NI; ii++) {
        accU[ii] = (f32x4){0.f, 0.f, 0.f, 0.f};
        #pragma unroll
        for (int j = 0; j < NN; j++) accY[ii][j] = (f32x4){0.f, 0.f, 0.f, 0.f};
    }

    #pragma unroll 1
    for (int k0 = 0; k0 < CC; k0 += 32) {
        if (k0) __syncthreads();
        // X + W2 staging DMA (swizzle carried in gaddr)
        #pragma unroll
        for (int t = 0; t < 15; t++) {
            GLD16(ws + gOff[t], SB + (sbase + t) * 1024);
            gOff[t] += 64;
        }
        // A frags for this chunk (global->reg; latency folds into the barrier drain)
        short8 af[NI][3];
        #pragma unroll
        for (int ii = 0; ii < NI; ii++)
            #pragma unroll
            for (int sp = 0; sp < 3; sp++)
                af[ii][sp] = *(const short8*)(ws + vAW
                    + (unsigned)(((IB + ii) * 3 + sp) * AW_PLANE) + (unsigned)k0 * 2);
        __syncthreads();

        // j-outer: X frags read once, shared across the i-set
        #pragma unroll
        for (int j = 0; j < NN; j++) {
            const unsigned char* xp = SB + (unsigned)(j * 3) * 2048u + xb;
            const short8 x0 = *(const short8*)(xp);
            const short8 x1 = *(const short8*)(xp + 2048);
            const short8 x2 = *(const short8*)(xp + 4096);
            #pragma unroll
            for (int ii = 0; ii < NI; ii++) {
                f32x4 c = accY[ii][j];
                c = MF(af[ii][0], x0, c);
                c = MF(af[ii][0], x1, c);
                c = MF(af[ii][1], x0, c);
                c = MF(af[ii][1], x1, c);
                c = MF(af[ii][0], x2, c);
                c = MF(af[ii][2], x0, c);
                accY[ii][j] = c;
            }
            if (j >= IB && j < IB + NI) {        // compile-time on unroll index
                const int ui = j - IB;
                // W2 frags from LDS (plane i*3+sp with i == j here)
                const unsigned char* wp = SB + 30720u + (unsigned)(j * 3) * 2048u + wb;
                const short8 w0f = *(const short8*)(wp);
                const short8 w1f = *(const short8*)(wp + 2048);
                const short8 w2f = *(const short8*)(wp + 4096);
                f32x4 u = accU[ui];
                u = MF(w0f, x0, u);
                u = MF(w0f, x1, u);
                u = MF(w1f, x0, u);
                u = MF(w1f, x1, u);
                u = MF(w0f, x2, u);
                u = MF(w2f, x0, u);
                accU[ui] = u;
            }
        }
    }

    // ---------------- epilogue (C/D: col=lane&15, row=qd*4+reg) ----------------
    const int sg  = s0 + 16 * sh + m_;
    const int og0 = o0 + 16 * oh + 4 * qd;

    float xe[NN][4];
    #pragma unroll
    for (int j = 0; j < NN; j++) {
        const float* px = x + (size_t)((j * BB + b) * CC + og0) * SSP + sg;
        #pragma unroll
        for (int r = 0; r < 4; r++) xe[j][r] = px[r * SSP];
    }

    #pragma unroll
    for (int ii = 0; ii < NI; ii++) {
        const int i = IB + ii;
        #pragma unroll
        for (int r = 0; r < 4; r++) {
            const float uu = accU[ii][r] + bias[i * CC + og0 + r];
            float e[NN]; float mx = 0.f;
            #pragma unroll
            for (int j = 0; j < NN; j++) {
                float d = fabsf(xe[j][r] - (accY[ii][j][r] + uu));
                d = (d > THRESHV) ? d : 0.f;
                e[j] = d; mx = fmaxf(mx, d);
            }
            float sum = 0.f, hv = 0.f;
            #pragma unroll
            for (int j = 0; j < NN; j++) {
                const float p = __expf(e[j] - mx);
                sum += p; hv += p * xe[j][r];
            }
            out[(size_t)((i * BB + b) * CC + og0 + r) * SSP + sg] = hv / sum;
        }
    }
}

// ================= fallback (R2 kernel, self-splitting; known-good) ==========
static __device__ __forceinline__ void st4(unsigned short* p, unsigned short a,
                                           unsigned short b, unsigned short c, unsigned short d) {
    ushort4 v; v.x = a; v.y = b; v.z = c; v.w = d;
    *(ushort4*)p = v;
}
#define XB 15360
__global__ __launch_bounds__(512, 2)
void fub_mfma(const float* __restrict__ x, const float* __restrict__ w,
              const float* __restrict__ bias, float* __restrict__ out)
{
    __shared__ unsigned short S[30720];
    const int tid = threadIdx.x;
    const int b = blockIdx.z, o0 = blockIdx.y * 32, s0 = blockIdx.x * 32;
    const int lane = tid & 63, wv = tid >> 6;
    const int q = wv & 3, oh = q >> 1, sh = q & 1, iset = wv >> 2, qd = lane >> 4;
    const int sub = tid >> 8, t = tid & 255;
    const int wo = t >> 3, wkg = t & 7, xs = t & 31, xkq = t >> 5;
    const int wbase = wo * 32 + (((wkg >> 1) ^ ((wo >> 1) & 3)) << 3) + ((wkg & 1) << 2);
    const int xbase = xs * 32 + (((xkq >> 1) ^ ((xs >> 1) & 3)) << 3) + ((xkq & 1) << 2);
    const int ar = 16 * oh + (lane & 15), xr = 16 * sh + (lane & 15);
    const int asw8 = ((qd ^ ((ar >> 1) & 3)) << 3), xsw8 = ((qd ^ ((xr >> 1) & 3)) << 3);
    const int arow32 = ar * 32, xrow32 = xr * 32;
    f32x4 accY[3][5]; f32x4 accU[3];
    #pragma unroll
    for (int ii = 0; ii < 3; ii++) {
        accU[ii] = (f32x4){0.f, 0.f, 0.f, 0.f};
        #pragma unroll
        for (int j = 0; j < NN; j++) accY[ii][j] = (f32x4){0.f, 0.f, 0.f, 0.f};
    }
    float w2sav[3][4];
    #pragma unroll 1
    for (int k0 = 0; k0 < CC; k0 += 32) {
        if (k0) __syncthreads();
        #pragma unroll
        for (int rep = 0; rep < 3; rep++) {
            const int i = rep * 2 + sub;
            if (i < NN) {
                const float* gw = w + (size_t)(i * CC + o0 + wo) * (2 * CC) + k0 + wkg * 4;
                const float4 w1 = *(const float4*)gw;
                const float4 w2 = *(const float4*)(gw + CC);
                w2sav[rep][0] = w2.x; w2sav[rep][1] = w2.y; w2sav[rep][2] = w2.z; w2sav[rep][3] = w2.w;
                float av[4] = {w1.x + w2.x, w1.y + w2.y, w1.z + w2.z, w1.w + w2.w};
                unsigned short h[4], m[4], l[4];
                #pragma unroll
                for (int r = 0; r < 4; r++) split3(av[r], h[r], m[r], l[r]);
                unsigned short* p = &S[i * 3 * 1024 + wbase];
                st4(p, h[0], h[1], h[2], h[3]); st4(p + 1024, m[0], m[1], m[2], m[3]); st4(p + 2048, l[0], l[1], l[2], l[3]);
            }
        }
        #pragma unroll
        for (int rep = 0; rep < 3; rep++) {
            const int j = rep * 2 + sub;
            if (j < NN) {
                const float* gx = x + (size_t)((j * BB + b) * CC + k0 + xkq * 4) * SSP + s0 + xs;
                float v[4] = {gx[0], gx[SSP], gx[2 * SSP], gx[3 * SSP]};
                unsigned short h[4], m[4], l[4];
                #pragma unroll
                for (int r = 0; r < 4; r++) split3(v[r], h[r], m[r], l[r]);
                unsigned short* p = &S[XB + j * 3 * 1024 + xbase];
                st4(p, h[0], h[1], h[2], h[3]); st4(p + 1024, m[0], m[1], m[2], m[3]); st4(p + 2048, l[0], l[1], l[2], l[3]);
            }
        }
        __syncthreads();
        short8 xf[NN][3];
        #pragma unroll
        for (int j = 0; j < NN; j++)
            #pragma unroll
            for (int sp = 0; sp < 3; sp++)
                xf[j][sp] = *(const short8*)&S[XB + (j * 3 + sp) * 1024 + xrow32 + xsw8];
#define YPL(IB_, NI_)                                                           \
        {                                                                       \
            _Pragma("unroll")                                                   \
            for (int ii = 0; ii < NI_; ii++) {                                  \
                const int i = IB_ + ii;                                         \
                const unsigned short* ap = &S[i * 3 * 1024 + arow32 + asw8];    \
                const short8 ah = *(const short8*)(ap);                         \
                const short8 am = *(const short8*)(ap + 1024);                  \
                const short8 al = *(const short8*)(ap + 2048);                  \
                _Pragma("unroll")                                               \
                for (int j = 0; j < NN; j++) {                                  \
                    f32x4 c = accY[ii][j];                                      \
                    c = MF(ah, xf[j][0], c); c = MF(ah, xf[j][1], c);           \
                    c = MF(am, xf[j][0], c); c = MF(am, xf[j][1], c);           \
                    c = MF(ah, xf[j][2], c); c = MF(al, xf[j][0], c);           \
                    accY[ii][j] = c;                                            \
                }                                                               \
            }                                                                   \
        }
        if (iset == 0) { YPL(0, 2) } else { YPL(2, 3) }
        __syncthreads();
        #pragma unroll
        for (int rep = 0; rep < 3; rep++) {
            const int i = rep * 2 + sub;
            if (i < NN) {
                unsigned short h[4], m[4], l[4];
                #pragma unroll
                for (int r = 0; r < 4; r++) split3(w2sav[rep][r], h[r], m[r], l[r]);
                unsigned short* p = &S[i * 3 * 1024 + wbase];
                st4(p, h[0], h[1], h[2], h[3]); st4(p + 1024, m[0], m[1], m[2], m[3]); st4(p + 2048, l[0], l[1], l[2], l[3]);
            }
        }
        __syncthreads();
#define UPL(IB_, NI_)                                                           \
        {                                                                       \
            _Pragma("unroll")                                                   \
            for (int ii = 0; ii < NI_; ii++) {                                  \
                const int i = IB_ + ii;                                         \
                const unsigned short* wp = &S[i * 3 * 1024 + arow32 + asw8];    \
                const short8 wh = *(const short8*)(wp);                         \
                const short8 wm = *(const short8*)(wp + 1024);                  \
                const short8 wl = *(const short8*)(wp + 2048);                  \
                f32x4 u = accU[ii];                                             \
                u = MF(wh, xf[i][0], u); u = MF(wh, xf[i][1], u);               \
                u = MF(wm, xf[i][0], u); u = MF(wm, xf[i][1], u);               \
                u = MF(wh, xf[i][2], u); u = MF(wl, xf[i][0], u);               \
                accU[ii] = u;                                                   \
            }                                                                   \
        }
        if (iset == 0) { UPL(0, 2) } else { UPL(2, 3) }
    }
    const int sg = s0 + 16 * sh + (lane & 15);
    const int og0 = o0 + 16 * oh + 4 * qd;
    float xe[NN][4];
    #pragma unroll
    for (int j = 0; j < NN; j++) {
        const float* px = x + (size_t)((j * BB + b) * CC + og0) * SSP + sg;
        #pragma unroll
        for (int r = 0; r < 4; r++) xe[j][r] = px[r * SSP];
    }
#define EPI(IB_, NI_)                                                           \
    {                                                                           \
        _Pragma("unroll")                                                       \
        for (int ii = 0; ii < NI_; ii++) {                                      \
            const int i = IB_ + ii;                                             \
            _Pragma("unroll")                                                   \
            for (int r = 0; r < 4; r++) {                                       \
                const float uu = accU[ii][r] + bias[i * CC + og0 + r];          \
                float e[NN]; float mx = 0.f;                                    \
                _Pragma("unroll")                                               \
                for (int j = 0; j < NN; j++) {                                  \
                    float d = fabsf(xe[j][r] - (accY[ii][j][r] + uu));          \
                    d = (d > THRESHV) ? d : 0.f;                                \
                    e[j] = d; mx = fmaxf(mx, d);                                \
                }                                                               \
                float sum = 0.f, hv = 0.f;                                      \
                _Pragma("unroll")                                               \
                for (int j = 0; j < NN; j++) {                                  \
                    const float p = __expf(e[j] - mx);                          \
                    sum += p; hv += p * xe[j][r];                               \
                }                                                               \
                out[(size_t)((i * BB + b) * CC + og0 + r) * SSP + sg] = hv / sum; \
            }                                                                   \
        }                                                                       \
    }
    if (iset == 0) { EPI(0, 2) } else { EPI(2, 3) }
}

extern "C" void kernel_launch(void* const* d_in, const int* in_sizes, int n_in,
                              void* d_out, int out_size, void* d_ws, size_t ws_size,
                              hipStream_t stream) {
    const float* x      = (const float*)d_in[0];
    const float* conv_w = (const float*)d_in[1];
    const float* conv_b = (const float*)d_in[2];
    float* out = (float*)d_out;

    if (ws_size >= WS_NEED) {
        unsigned char* ws = (unsigned char*)d_ws;
        prep_all<<<480, 256, 0, stream>>>(x, conv_w, ws);
        dim3 grid(SSP / 32, CC / 32, BB);   // 2048 blocks, all 5 i fused
        fub_main<0, 5><<<grid, 256, 0, stream>>>(x, conv_b, ws, out);
    } else {
        fub_mfma<<<dim3(SSP / 32, CC / 32, BB), 512, 0, stream>>>(x, conv_w, conv_b, out);
    }
}

// Round 8
// 291.120 us; speedup vs baseline: 1.8021x; 1.0249x over previous
//
#include <hip/hip_runtime.h>
#include <math.h>

// N=5, B=8, C=256, H*W=1024
#define NN 5
#define CC 256
#define SSP 1024
#define BB 8
#define THRESHV 0.3f

typedef __attribute__((ext_vector_type(8))) short short8;   // 8 bf16 = one MFMA A/B frag
typedef __attribute__((ext_vector_type(4))) float f32x4;    // MFMA 16x16 accumulator

// ---------------- ws layout (bytes) ----------------
// X split planes, k-minor: [(j*8+b)*3+sp][s:1024][k:256] bf16
#define XW_OFF   0ull
#define XW_PLANE ((size_t)SSP * CC * 2)                 // 524288
#define XW_SIZE  ((size_t)NN * BB * 3 * XW_PLANE)       // 62,914,560
// A = W1+W2 split planes, k-minor: [i*3+sp][o:256][k:256]
#define AW_OFF   XW_SIZE
#define AW_PLANE ((size_t)CC * CC * 2)                  // 131072
#define AW_SIZE  ((size_t)NN * 3 * AW_PLANE)            // 1,966,080
#define W2_OFF   (AW_OFF + AW_SIZE)
#define WS_NEED  (W2_OFF + AW_SIZE)                     // ~63.8 MiB

// ---- exact 3-way bf16 split (Dekker-style; residuals exact in fp32) ----
static __device__ __forceinline__ unsigned short f2bf(float f) {
    unsigned int u = __builtin_bit_cast(unsigned int, f);
    u = u + 0x7fffu + ((u >> 16) & 1u);          // RNE to bf16
    return (unsigned short)(u >> 16);
}
static __device__ __forceinline__ float bf2f(unsigned short h) {
    unsigned int u = ((unsigned int)h) << 16;
    return __builtin_bit_cast(float, u);
}
static __device__ __forceinline__ void split3(float a, unsigned short& h,
                                              unsigned short& m, unsigned short& l) {
    h = f2bf(a); float r1 = a - bf2f(h);
    m = f2bf(r1); float r2 = r1 - bf2f(m);
    l = f2bf(r2);
}
static __device__ __forceinline__ f32x4 MF(short8 a, short8 b, f32x4 c) {
    return __builtin_amdgcn_mfma_f32_16x16x32_bf16(a, b, c, 0, 0, 0);
}

// async global->LDS, 16B per lane; LDS dest = uniform base + lane*16
#define GLD16(gp, lp) __builtin_amdgcn_global_load_lds(                          \
        (const __attribute__((address_space(1))) unsigned int*)(gp),             \
        (__attribute__((address_space(3))) unsigned int*)(lp), 16, 0, 0)

// ================= merged pre-pass =================
// Blocks 0..1279 : X split+transpose via LDS, ONE (jb,kc,sc) tile per block.
//   R7 ran 320 fat blocks with a serial 4-iteration sc loop (~1.9 blocks/CU,
//   latency-bound: each iteration = strided-load chain -> LDS -> barrier ->
//   write). Hoisting sc into the grid gives 1280 light blocks (~5/CU) so the
//   chains overlap across blocks. Same swizzle, bit-identical bytes.
// Blocks 1280..1439: weight split (identical math to the original prep_w).
// LDS tile: 3 planes x 256 s-rows x PXS(=40) shorts. Unit swizzle
// po = o ^ (s&3) ^ ((s>>3)&3) keeps b32 writes and b128 reads <=2-way.
#define PXS 40
__global__ __launch_bounds__(256)
void prep_all(const float* __restrict__ x, const float* __restrict__ w,
              unsigned char* __restrict__ ws) {
    __shared__ unsigned short S[3 * 256 * PXS];      // 61440 B
    const int tid = threadIdx.x;

    if (blockIdx.x >= 1280) {
        // ---------------- weight split (verbatim math) ----------------------
        const int id = (blockIdx.x - 1280) * 256 + tid;  // 40960 = 5*256*32
        const int i  = id >> 13;
        const int o  = (id >> 5) & 255;
        const int ko = id & 31;                          // k-oct
        const float* gw = w + (size_t)(i * CC + o) * (2 * CC) + ko * 8;
        float av[8], wv[8];
        #pragma unroll
        for (int kk = 0; kk < 8; kk++) {
            wv[kk] = gw[CC + kk];
            av[kk] = gw[kk] + wv[kk];
        }
        unsigned short h[8], m[8], l[8];
        short8 H, M, L;
        #pragma unroll
        for (int kk = 0; kk < 8; kk++) split3(av[kk], h[kk], m[kk], l[kk]);
        #pragma unroll
        for (int kk = 0; kk < 8; kk++) { H[kk] = (short)h[kk]; M[kk] = (short)m[kk]; L[kk] = (short)l[kk]; }
        {
            unsigned char* p = ws + AW_OFF + (size_t)((i * 3) * CC + o) * 512 + ko * 16;
            *(short8*)(p)                = H;
            *(short8*)(p + CC * 512)     = M;
            *(short8*)(p + 2 * CC * 512) = L;
        }
        #pragma unroll
        for (int kk = 0; kk < 8; kk++) split3(wv[kk], h[kk], m[kk], l[kk]);
        #pragma unroll
        for (int kk = 0; kk < 8; kk++) { H[kk] = (short)h[kk]; M[kk] = (short)m[kk]; L[kk] = (short)l[kk]; }
        {
            unsigned char* p = ws + W2_OFF + (size_t)((i * 3) * CC + o) * 512 + ko * 16;
            *(short8*)(p)                = H;
            *(short8*)(p + CC * 512)     = M;
            *(short8*)(p + 2 * CC * 512) = L;
        }
        return;
    }

    // ---------------- X split + transpose (blocks 0..1279) ------------------
    const int blk = blockIdx.x;          // 1280 = 40 jb * 8 kc * 4 sc
    const int sc  = blk & 3;
    const int kc  = (blk >> 2) & 7;
    const int jb  = blk >> 5;            // j*8+b
    const int k0  = kc * 32;
    unsigned char* const pl0 = ws + XW_OFF + (size_t)(jb * 3) * XW_PLANE
                             + (size_t)(k0 * 2);
    const int swk = (tid & 3) ^ ((tid >> 3) & 3);     // writer-row swizzle key

    const int s = sc * 256 + tid;
    const float* gx = x + ((size_t)jb * CC + k0) * SSP + s;
    // read coalesced, split, stage in LDS (row = this thread's s)
    #pragma unroll
    for (int kp = 0; kp < 16; kp++) {            // pairs of k
        const float v0 = gx[(size_t)(2 * kp) * SSP];
        const float v1 = gx[(size_t)(2 * kp + 1) * SSP];
        unsigned short h0, m0, l0, h1, m1, l1;
        split3(v0, h0, m0, l0);
        split3(v1, h1, m1, l1);
        const int po  = (kp >> 2) ^ swk;          // swizzled 16B unit
        const int idx = tid * PXS + po * 8 + (kp & 3) * 2;
        *(unsigned int*)&S[idx]             = (unsigned)h0 | ((unsigned)h1 << 16);
        *(unsigned int*)&S[idx + 256 * PXS] = (unsigned)m0 | ((unsigned)m1 << 16);
        *(unsigned int*)&S[idx + 512 * PXS] = (unsigned)l0 | ((unsigned)l1 << 16);
    }
    __syncthreads();
    // write out transposed: 4 lanes cover one 64B s-row segment
    #pragma unroll
    for (int sp = 0; sp < 3; sp++) {
        #pragma unroll
        for (int it = 0; it < 4; it++) {
            const int u   = it * 256 + tid;
            const int su  = u >> 2, ko = u & 3;
            const int pko = ko ^ (su & 3) ^ ((su >> 3) & 3);
            const short8 v = *(const short8*)&S[sp * 256 * PXS + su * PXS + pko * 8];
            *(short8*)(pl0 + (size_t)sp * XW_PLANE
                       + (size_t)(sc * 256 + su) * 512 + ko * 16) = v;
        }
    }
}

// ================= main fused kernel (R2 structure, known-good 218us) ========
// LDS (61440 B): X planes [0..30719]: 15 planes (j*3+sp) x 2048B.
//                W2 planes [30720..61439]: 15 planes (i*3+sp) x 2048B.
// Both staged via global_load_lds with the bank swizzle carried in the per-lane
// DMA global address. A frags global->reg before the barrier (latency folds
// into the drain). 60 GLD16 slots per chunk = exactly 15 per wave.
// NOTE (R3-R6): explicit dbuf/counted-vmcnt/phase/all-register variants all
// lost to this plain 2-barrier loop; acc(120 AGPR)+VGPR(128) = 248/512 regs
// pins occupancy at 2 waves/SIMD, so cross-block overlap is the only hiding
// mechanism and extra sync structure only breaks it. Do not re-pipeline.
template<int IB, int NI>
__global__ __launch_bounds__(256, 2)
void fub_main(const float* __restrict__ x, const float* __restrict__ bias,
              const unsigned char* __restrict__ ws, float* __restrict__ out)
{
    __shared__ unsigned char SB[61440];

    const int tid  = threadIdx.x;
    const int b    = blockIdx.z;
    const int o0   = blockIdx.y * 32;
    const int s0   = blockIdx.x * 32;
    const int lane = tid & 63;
    const int w    = tid >> 6;            // wave 0..3 -> tile quarter
    const int oh   = w >> 1, sh = w & 1;
    const int qd   = lane >> 4;
    const int m_   = lane & 15;
    const int ar   = 16 * oh + m_;        // o row for A/W2 frags
    const int xr   = 16 * sh + m_;        // s row for X frags

    // ---- DMA staging: 60 slots over 4 waves (15 each) ----
    // slots 0..29 : X planes (p = slot>>1 = j*3+sp), rows are s-rows
    // slots 30..59: W2 planes (p = (slot-30)>>1 = i*3+sp), rows are o-rows
    const int sbase = w * 15;
    unsigned gOff[15];
    #pragma unroll
    for (int t = 0; t < 15; t++) {
        const int slot = sbase + t;
        if (slot < 30) {
            const int p  = slot >> 1;              // plane 0..14 = j*3+sp
            const int jj = p / 3, sp = p - 3 * jj;
            const int u  = (slot & 1) * 64 + lane; // unit within plane
            const int sr = u >> 2;
            const int oc = (u & 3) ^ (sr & 3) ^ ((sr >> 2) & 3);
            gOff[t] = (unsigned)(((jj * BB + b) * 3 + sp) * XW_PLANE)
                    + (unsigned)((s0 + sr) * 512 + oc * 16);
        } else {
            const int sl = slot - 30;
            const int p  = sl >> 1;                // plane 0..14 = i*3+sp
            const int u  = (sl & 1) * 64 + lane;
            const int sr = u >> 2;                 // o-row within tile
            const int oc = (u & 3) ^ (sr & 3) ^ ((sr >> 2) & 3);
            gOff[t] = (unsigned)W2_OFF
                    + (unsigned)((p * CC + o0 + sr) * 512 + oc * 16);
        }
    }

    // ---- A frag per-lane base (k-minor planes) ----
    const unsigned vAW = (unsigned)AW_OFF + (unsigned)(o0 + ar) * 512u + (unsigned)qd * 16u;
    // X frag LDS byte offset (within plane, swizzled)
    const unsigned xb = (unsigned)(xr * 4 + (qd ^ (xr & 3) ^ ((xr >> 2) & 3))) * 16u;
    // W2 frag LDS byte offset (within plane, swizzled; o-row = ar)
    const unsigned wb = (unsigned)(ar * 4 + (qd ^ (ar & 3) ^ ((ar >> 2) & 3))) * 16u;

    f32x4 accY[NI][NN];
    f32x4 accU[NI];
    #pragma unroll
    for (int ii = 0; ii < NI; ii++) {
        accU[ii] = (f32x4){0.f, 0.f, 0.f, 0.f};
        #pragma unroll
        for (int j = 0; j < NN; j++) accY[ii][j] = (f32x4){0.f, 0.f, 0.f, 0.f};
    }

    #pragma unroll 1
    for (int k0 = 0; k0 < CC; k0 += 32) {
        if (k0) __syncthreads();
        // X + W2 staging DMA (swizzle carried in gaddr)
        #pragma unroll
        for (int t = 0; t < 15; t++) {
            GLD16(ws + gOff[t], SB + (sbase + t) * 1024);
            gOff[t] += 64;
        }
        // A frags for this chunk (global->reg; latency folds into the barrier drain)
        short8 af[NI][3];
        #pragma unroll
        for (int ii = 0; ii < NI; ii++)
            #pragma unroll
            for (int sp = 0; sp < 3; sp++)
                af[ii][sp] = *(const short8*)(ws + vAW
                    + (unsigned)(((IB + ii) * 3 + sp) * AW_PLANE) + (unsigned)k0 * 2);
        __syncthreads();

        // j-outer: X frags read once, shared across the i-set
        #pragma unroll
        for (int j = 0; j < NN; j++) {
            const unsigned char* xp = SB + (unsigned)(j * 3) * 2048u + xb;
            const short8 x0 = *(const short8*)(xp);
            const short8 x1 = *(const short8*)(xp + 2048);
            const short8 x2 = *(const short8*)(xp + 4096);
            #pragma unroll
            for (int ii = 0; ii < NI; ii++) {
                f32x4 c = accY[ii][j];
                c = MF(af[ii][0], x0, c);
                c = MF(af[ii][0], x1, c);
                c = MF(af[ii][1], x0, c);
                c = MF(af[ii][1], x1, c);
                c = MF(af[ii][0], x2, c);
                c = MF(af[ii][2], x0, c);
                accY[ii][j] = c;
            }
            if (j >= IB && j < IB + NI) {        // compile-time on unroll index
                const int ui = j - IB;
                // W2 frags from LDS (plane i*3+sp with i == j here)
                const unsigned char* wp = SB + 30720u + (unsigned)(j * 3) * 2048u + wb;
                const short8 w0f = *(const short8*)(wp);
                const short8 w1f = *(const short8*)(wp + 2048);
                const short8 w2f = *(const short8*)(wp + 4096);
                f32x4 u = accU[ui];
                u = MF(w0f, x0, u);
                u = MF(w0f, x1, u);
                u = MF(w1f, x0, u);
                u = MF(w1f, x1, u);
                u = MF(w0f, x2, u);
                u = MF(w2f, x0, u);
                accU[ui] = u;
            }
        }
    }

    // ---------------- epilogue (C/D: col=lane&15, row=qd*4+reg) ----------------
    const int sg  = s0 + 16 * sh + m_;
    const int og0 = o0 + 16 * oh + 4 * qd;

    float xe[NN][4];
    #pragma unroll
    for (int j = 0; j < NN; j++) {
        const float* px = x + (size_t)((j * BB + b) * CC + og0) * SSP + sg;
        #pragma unroll
        for (int r = 0; r < 4; r++) xe[j][r] = px[r * SSP];
    }

    #pragma unroll
    for (int ii = 0; ii < NI; ii++) {
        const int i = IB + ii;
        #pragma unroll
        for (int r = 0; r < 4; r++) {
            const float uu = accU[ii][r] + bias[i * CC + og0 + r];
            float e[NN]; float mx = 0.f;
            #pragma unroll
            for (int j = 0; j < NN; j++) {
                float d = fabsf(xe[j][r] - (accY[ii][j][r] + uu));
                d = (d > THRESHV) ? d : 0.f;
                e[j] = d; mx = fmaxf(mx, d);
            }
            float sum = 0.f, hv = 0.f;
            #pragma unroll
            for (int j = 0; j < NN; j++) {
                const float p = __expf(e[j] - mx);
                sum += p; hv += p * xe[j][r];
            }
            out[(size_t)((i * BB + b) * CC + og0 + r) * SSP + sg] = hv / sum;
        }
    }
}

// ================= fallback (R2 kernel, self-splitting; known-good) ==========
static __device__ __forceinline__ void st4(unsigned short* p, unsigned short a,
                                           unsigned short b, unsigned short c, unsigned short d) {
    ushort4 v; v.x = a; v.y = b; v.z = c; v.w = d;
    *(ushort4*)p = v;
}
#define XB 15360
__global__ __launch_bounds__(512, 2)
void fub_mfma(const float* __restrict__ x, const float* __restrict__ w,
              const float* __restrict__ bias, float* __restrict__ out)
{
    __shared__ unsigned short S[30720];
    const int tid = threadIdx.x;
    const int b = blockIdx.z, o0 = blockIdx.y * 32, s0 = blockIdx.x * 32;
    const int lane = tid & 63, wv = tid >> 6;
    const int q = wv & 3, oh = q >> 1, sh = q & 1, iset = wv >> 2, qd = lane >> 4;
    const int sub = tid >> 8, t = tid & 255;
    const int wo = t >> 3, wkg = t & 7, xs = t & 31, xkq = t >> 5;
    const int wbase = wo * 32 + (((wkg >> 1) ^ ((wo >> 1) & 3)) << 3) + ((wkg & 1) << 2);
    const int xbase = xs * 32 + (((xkq >> 1) ^ ((xs >> 1) & 3)) << 3) + ((xkq & 1) << 2);
    const int ar = 16 * oh + (lane & 15), xr = 16 * sh + (lane & 15);
    const int asw8 = ((qd ^ ((ar >> 1) & 3)) << 3), xsw8 = ((qd ^ ((xr >> 1) & 3)) << 3);
    const int arow32 = ar * 32, xrow32 = xr * 32;
    f32x4 accY[3][5]; f32x4 accU[3];
    #pragma unroll
    for (int ii = 0; ii < 3; ii++) {
        accU[ii] = (f32x4){0.f, 0.f, 0.f, 0.f};
        #pragma unroll
        for (int j = 0; j < NN; j++) accY[ii][j] = (f32x4){0.f, 0.f, 0.f, 0.f};
    }
    float w2sav[3][4];
    #pragma unroll 1
    for (int k0 = 0; k0 < CC; k0 += 32) {
        if (k0) __syncthreads();
        #pragma unroll
        for (int rep = 0; rep < 3; rep++) {
            const int i = rep * 2 + sub;
            if (i < NN) {
                const float* gw = w + (size_t)(i * CC + o0 + wo) * (2 * CC) + k0 + wkg * 4;
                const float4 w1 = *(const float4*)gw;
                const float4 w2 = *(const float4*)(gw + CC);
                w2sav[rep][0] = w2.x; w2sav[rep][1] = w2.y; w2sav[rep][2] = w2.z; w2sav[rep][3] = w2.w;
                float av[4] = {w1.x + w2.x, w1.y + w2.y, w1.z + w2.z, w1.w + w2.w};
                unsigned short h[4], m[4], l[4];
                #pragma unroll
                for (int r = 0; r < 4; r++) split3(av[r], h[r], m[r], l[r]);
                unsigned short* p = &S[i * 3 * 1024 + wbase];
                st4(p, h[0], h[1], h[2], h[3]); st4(p + 1024, m[0], m[1], m[2], m[3]); st4(p + 2048, l[0], l[1], l[2], l[3]);
            }
        }
        #pragma unroll
        for (int rep = 0; rep < 3; rep++) {
            const int j = rep * 2 + sub;
            if (j < NN) {
                const float* gx = x + (size_t)((j * BB + b) * CC + k0 + xkq * 4) * SSP + s0 + xs;
                float v[4] = {gx[0], gx[SSP], gx[2 * SSP], gx[3 * SSP]};
                unsigned short h[4], m[4], l[4];
                #pragma unroll
                for (int r = 0; r < 4; r++) split3(v[r], h[r], m[r], l[r]);
                unsigned short* p = &S[XB + j * 3 * 1024 + xbase];
                st4(p, h[0], h[1], h[2], h[3]); st4(p + 1024, m[0], m[1], m[2], m[3]); st4(p + 2048, l[0], l[1], l[2], l[3]);
            }
        }
        __syncthreads();
        short8 xf[NN][3];
        #pragma unroll
        for (int j = 0; j < NN; j++)
            #pragma unroll
            for (int sp = 0; sp < 3; sp++)
                xf[j][sp] = *(const short8*)&S[XB + (j * 3 + sp) * 1024 + xrow32 + xsw8];
#define YPL(IB_, NI_)                                                           \
        {                                                                       \
            _Pragma("unroll")                                                   \
            for (int ii = 0; ii < NI_; ii++) {                                  \
                const int i = IB_ + ii;                                         \
                const unsigned short* ap = &S[i * 3 * 1024 + arow32 + asw8];    \
                const short8 ah = *(const short8*)(ap);                         \
                const short8 am = *(const short8*)(ap + 1024);                  \
                const short8 al = *(const short8*)(ap + 2048);                  \
                _Pragma("unroll")                                               \
                for (int j = 0; j < NN; j++) {                                  \
                    f32x4 c = accY[ii][j];                                      \
                    c = MF(ah, xf[j][0], c); c = MF(ah, xf[j][1], c);           \
                    c = MF(am, xf[j][0], c); c = MF(am, xf[j][1], c);           \
                    c = MF(ah, xf[j][2], c); c = MF(al, xf[j][0], c);           \
                    accY[ii][j] = c;                                            \
                }                                                               \
            }                                                                   \
        }
        if (iset == 0) { YPL(0, 2) } else { YPL(2, 3) }
        __syncthreads();
        #pragma unroll
        for (int rep = 0; rep < 3; rep++) {
            const int i = rep * 2 + sub;
            if (i < NN) {
                unsigned short h[4], m[4], l[4];
                #pragma unroll
                for (int r = 0; r < 4; r++) split3(w2sav[rep][r], h[r], m[r], l[r]);
                unsigned short* p = &S[i * 3 * 1024 + wbase];
                st4(p, h[0], h[1], h[2], h[3]); st4(p + 1024, m[0], m[1], m[2], m[3]); st4(p + 2048, l[0], l[1], l[2], l[3]);
            }
        }
        __syncthreads();
#define UPL(IB_, NI_)                                                           \
        {                                                                       \
            _Pragma("unroll")                                                   \
            for (int ii = 0; ii < NI_; ii++) {                                  \
                const int i = IB_ + ii;                                         \
                const unsigned short* wp = &S[i * 3 * 1024 + arow32 + asw8];    \
                const short8 wh = *(const short8*)(wp);                         \
                const short8 wm = *(const short8*)(wp + 1024);                  \
                const short8 wl = *(const short8*)(wp + 2048);                  \
                f32x4 u = accU[ii];                                             \
                u = MF(wh, xf[i][0], u); u = MF(wh, xf[i][1], u);               \
                u = MF(wm, xf[i][0], u); u = MF(wm, xf[i][1], u);               \
                u = MF(wh, xf[i][2], u); u = MF(wl, xf[i][0], u);               \
                accU[ii] = u;                                                   \
            }                                                                   \
        }
        if (iset == 0) { UPL(0, 2) } else { UPL(2, 3) }
    }
    const int sg = s0 + 16 * sh + (lane & 15);
    const int og0 = o0 + 16 * oh + 4 * qd;
    float xe[NN][4];
    #pragma unroll
    for (int j = 0; j < NN; j++) {
        const float* px = x + (size_t)((j * BB + b) * CC + og0) * SSP + sg;
        #pragma unroll
        for (int r = 0; r < 4; r++) xe[j][r] = px[r * SSP];
    }
#define EPI(IB_, NI_)                                                           \
    {                                                                           \
        _Pragma("unroll")                                                       \
        for (int ii = 0; ii < NI_; ii++) {                                      \
            const int i = IB_ + ii;                                             \
            _Pragma("unroll")                                                   \
            for (int r = 0; r < 4; r++) {                                       \
                const float uu = accU[ii][r] + bias[i * CC + og0 + r];          \
                float e[NN]; float mx = 0.f;                                    \
                _Pragma("unroll")                                               \
                for (int j = 0; j < NN; j++) {                                  \
                    float d = fabsf(xe[j][r] - (accY[ii][j][r] + uu));          \
                    d = (d > THRESHV) ? d : 0.f;                                \
                    e[j] = d; mx = fmaxf(mx, d);                                \
                }                                                               \
                float sum = 0.f, hv = 0.f;                                      \
                _Pragma("unroll")                                               \
                for (int j = 0; j < NN; j++) {                                  \
                    const float p = __expf(e[j] - mx);                          \
                    sum += p; hv += p * xe[j][r];                               \
                }                                                               \
                out[(size_t)((i * BB + b) * CC + og0 + r) * SSP + sg] = hv / sum; \
            }                                                                   \
        }                                                                       \
    }
    if (iset == 0) { EPI(0, 2) } else { EPI(2, 3) }
}

extern "C" void kernel_launch(void* const* d_in, const int* in_sizes, int n_in,
                              void* d_out, int out_size, void* d_ws, size_t ws_size,
                              hipStream_t stream) {
    const float* x      = (const float*)d_in[0];
    const float* conv_w = (const float*)d_in[1];
    const float* conv_b = (const float*)d_in[2];
    float* out = (float*)d_out;

    if (ws_size >= WS_NEED) {
        unsigned char* ws = (unsigned char*)d_ws;
        prep_all<<<1440, 256, 0, stream>>>(x, conv_w, ws);
        dim3 grid(SSP / 32, CC / 32, BB);   // 2048 blocks, all 5 i fused
        fub_main<0, 5><<<grid, 256, 0, stream>>>(x, conv_b, ws, out);
    } else {
        fub_mfma<<<dim3(SSP / 32, CC / 32, BB), 512, 0, stream>>>(x, conv_w, conv_b, out);
    }
}

// Round 9
// 286.491 us; speedup vs baseline: 1.8312x; 1.0162x over previous
//
#include <hip/hip_runtime.h>
#include <math.h>

// N=5, B=8, C=256, H*W=1024
#define NN 5
#define CC 256
#define SSP 1024
#define BB 8
#define THRESHV 0.3f

typedef __attribute__((ext_vector_type(8))) short short8;   // 8 bf16 = one MFMA A/B frag
typedef __attribute__((ext_vector_type(4))) float f32x4;    // MFMA 16x16 accumulator

// ---------------- ws layout (bytes) ----------------
// X split planes, k-minor: [(j*8+b)*3+sp][s:1024][k:256] bf16
#define XW_OFF   0ull
#define XW_PLANE ((size_t)SSP * CC * 2)                 // 524288
#define XW_SIZE  ((size_t)NN * BB * 3 * XW_PLANE)       // 62,914,560
// A = W1+W2 split planes, k-minor: [i*3+sp][o:256][k:256]
#define AW_OFF   XW_SIZE
#define AW_PLANE ((size_t)CC * CC * 2)                  // 131072
#define AW_SIZE  ((size_t)NN * 3 * AW_PLANE)            // 1,966,080
#define W2_OFF   (AW_OFF + AW_SIZE)
#define WS_NEED  (W2_OFF + AW_SIZE)                     // ~63.8 MiB

// ---- exact 3-way bf16 split (Dekker-style; residuals exact in fp32) ----
static __device__ __forceinline__ unsigned short f2bf(float f) {
    unsigned int u = __builtin_bit_cast(unsigned int, f);
    u = u + 0x7fffu + ((u >> 16) & 1u);          // RNE to bf16
    return (unsigned short)(u >> 16);
}
static __device__ __forceinline__ float bf2f(unsigned short h) {
    unsigned int u = ((unsigned int)h) << 16;
    return __builtin_bit_cast(float, u);
}
static __device__ __forceinline__ void split3(float a, unsigned short& h,
                                              unsigned short& m, unsigned short& l) {
    h = f2bf(a); float r1 = a - bf2f(h);
    m = f2bf(r1); float r2 = r1 - bf2f(m);
    l = f2bf(r2);
}
static __device__ __forceinline__ f32x4 MF(short8 a, short8 b, f32x4 c) {
    return __builtin_amdgcn_mfma_f32_16x16x32_bf16(a, b, c, 0, 0, 0);
}

// async global->LDS, 16B per lane; LDS dest = uniform base + lane*16
#define GLD16(gp, lp) __builtin_amdgcn_global_load_lds(                          \
        (const __attribute__((address_space(1))) unsigned int*)(gp),             \
        (__attribute__((address_space(3))) unsigned int*)(lp), 16, 0, 0)

// ================= merged pre-pass =================
// Blocks 0..2559 : X split+transpose via LDS, ONE (jb,kc,sc) 128-row tile per
//   block. R8's 256-row tile used 60KB LDS -> only 2 blocks/CU resident, so the
//   strided-read -> LDS -> write chains had no TLP to hide under (prep was
//   latency-bound at ~45us). 128-row tiles (30720B LDS) give 5 blocks/CU
//   (153.6KB of 160KB) = 20 waves/CU. Same swizzle scheme, bit-identical bytes.
// Blocks 2560..2719: weight split (identical math to the original prep_w).
// LDS tile: 3 planes x 128 s-rows x PXS(=40) shorts. Unit swizzle
// po = unit ^ (s&3) ^ ((s>>3)&3) keeps b32 writes and b128 reads <=2-way.
#define PXS 40
__global__ __launch_bounds__(256)
void prep_all(const float* __restrict__ x, const float* __restrict__ w,
              unsigned char* __restrict__ ws) {
    __shared__ unsigned short S[3 * 128 * PXS];      // 30720 B
    const int tid = threadIdx.x;

    if (blockIdx.x >= 2560) {
        // ---------------- weight split (verbatim math) ----------------------
        const int id = (blockIdx.x - 2560) * 256 + tid;  // 40960 = 5*256*32
        const int i  = id >> 13;
        const int o  = (id >> 5) & 255;
        const int ko = id & 31;                          // k-oct
        const float* gw = w + (size_t)(i * CC + o) * (2 * CC) + ko * 8;
        float av[8], wv[8];
        #pragma unroll
        for (int kk = 0; kk < 8; kk++) {
            wv[kk] = gw[CC + kk];
            av[kk] = gw[kk] + wv[kk];
        }
        unsigned short h[8], m[8], l[8];
        short8 H, M, L;
        #pragma unroll
        for (int kk = 0; kk < 8; kk++) split3(av[kk], h[kk], m[kk], l[kk]);
        #pragma unroll
        for (int kk = 0; kk < 8; kk++) { H[kk] = (short)h[kk]; M[kk] = (short)m[kk]; L[kk] = (short)l[kk]; }
        {
            unsigned char* p = ws + AW_OFF + (size_t)((i * 3) * CC + o) * 512 + ko * 16;
            *(short8*)(p)                = H;
            *(short8*)(p + CC * 512)     = M;
            *(short8*)(p + 2 * CC * 512) = L;
        }
        #pragma unroll
        for (int kk = 0; kk < 8; kk++) split3(wv[kk], h[kk], m[kk], l[kk]);
        #pragma unroll
        for (int kk = 0; kk < 8; kk++) { H[kk] = (short)h[kk]; M[kk] = (short)m[kk]; L[kk] = (short)l[kk]; }
        {
            unsigned char* p = ws + W2_OFF + (size_t)((i * 3) * CC + o) * 512 + ko * 16;
            *(short8*)(p)                = H;
            *(short8*)(p + CC * 512)     = M;
            *(short8*)(p + 2 * CC * 512) = L;
        }
        return;
    }

    // ---------------- X split + transpose (blocks 0..2559) ------------------
    const int blk = blockIdx.x;          // 2560 = 40 jb * 8 kc * 8 sc
    const int sc  = blk & 7;             // 128-row tile index
    const int kc  = (blk >> 3) & 7;
    const int jb  = blk >> 6;            // j*8+b
    const int k0  = kc * 32;
    unsigned char* const pl0 = ws + XW_OFF + (size_t)(jb * 3) * XW_PLANE
                             + (size_t)(k0 * 2);

    const int s   = tid & 127;           // row within tile
    const int kh  = tid >> 7;            // 0/1: 16-k half of the 32-k chunk
    const int swk = (s & 3) ^ ((s >> 3) & 3);     // row swizzle key

    const float* gx = x + ((size_t)jb * CC + k0 + kh * 16) * SSP + sc * 128 + s;
    // read coalesced (256B/instr per wave), split, stage in LDS
    #pragma unroll
    for (int lp = 0; lp < 8; lp++) {             // pairs of k within this half
        const float v0 = gx[(size_t)(2 * lp) * SSP];
        const float v1 = gx[(size_t)(2 * lp + 1) * SSP];
        unsigned short h0, m0, l0, h1, m1, l1;
        split3(v0, h0, m0, l0);
        split3(v1, h1, m1, l1);
        const int gp  = kh * 8 + lp;              // global k-pair 0..15
        const int po  = (gp >> 2) ^ swk;          // swizzled 16B unit
        const int idx = s * PXS + po * 8 + (gp & 3) * 2;
        *(unsigned int*)&S[idx]             = (unsigned)h0 | ((unsigned)h1 << 16);
        *(unsigned int*)&S[idx + 128 * PXS] = (unsigned)m0 | ((unsigned)m1 << 16);
        *(unsigned int*)&S[idx + 256 * PXS] = (unsigned)l0 | ((unsigned)l1 << 16);
    }
    __syncthreads();
    // write out transposed: 4 lanes cover one 64B s-row segment
    #pragma unroll
    for (int sp = 0; sp < 3; sp++) {
        #pragma unroll
        for (int it = 0; it < 2; it++) {
            const int u   = it * 256 + tid;       // 0..511
            const int su  = u >> 2, ko = u & 3;
            const int pko = ko ^ (su & 3) ^ ((su >> 3) & 3);
            const short8 v = *(const short8*)&S[sp * 128 * PXS + su * PXS + pko * 8];
            *(short8*)(pl0 + (size_t)sp * XW_PLANE
                       + (size_t)(sc * 128 + su) * 512 + ko * 16) = v;
        }
    }
}

// ================= main fused kernel (R2 structure, known-good 218us) ========
// LDS (61440 B): X planes [0..30719]: 15 planes (j*3+sp) x 2048B.
//                W2 planes [30720..61439]: 15 planes (i*3+sp) x 2048B.
// Both staged via global_load_lds with the bank swizzle carried in the per-lane
// DMA global address. A frags global->reg before the barrier (latency folds
// into the drain). 60 GLD16 slots per chunk = exactly 15 per wave.
// NOTE (R3-R6): explicit dbuf/counted-vmcnt/phase/all-register variants all
// lost to this plain 2-barrier loop; acc(120 AGPR)+VGPR(128) = ~248/512 regs
// pins occupancy at 2 waves/SIMD, so cross-block overlap is the only hiding
// mechanism and extra sync structure only breaks it. Do not re-pipeline.
template<int IB, int NI>
__global__ __launch_bounds__(256, 2)
void fub_main(const float* __restrict__ x, const float* __restrict__ bias,
              const unsigned char* __restrict__ ws, float* __restrict__ out)
{
    __shared__ unsigned char SB[61440];

    const int tid  = threadIdx.x;
    const int b    = blockIdx.z;
    const int o0   = blockIdx.y * 32;
    const int s0   = blockIdx.x * 32;
    const int lane = tid & 63;
    const int w    = tid >> 6;            // wave 0..3 -> tile quarter
    const int oh   = w >> 1, sh = w & 1;
    const int qd   = lane >> 4;
    const int m_   = lane & 15;
    const int ar   = 16 * oh + m_;        // o row for A/W2 frags
    const int xr   = 16 * sh + m_;        // s row for X frags

    // ---- DMA staging: 60 slots over 4 waves (15 each) ----
    // slots 0..29 : X planes (p = slot>>1 = j*3+sp), rows are s-rows
    // slots 30..59: W2 planes (p = (slot-30)>>1 = i*3+sp), rows are o-rows
    const int sbase = w * 15;
    unsigned gOff[15];
    #pragma unroll
    for (int t = 0; t < 15; t++) {
        const int slot = sbase + t;
        if (slot < 30) {
            const int p  = slot >> 1;              // plane 0..14 = j*3+sp
            const int jj = p / 3, sp = p - 3 * jj;
            const int u  = (slot & 1) * 64 + lane; // unit within plane
            const int sr = u >> 2;
            const int oc = (u & 3) ^ (sr & 3) ^ ((sr >> 2) & 3);
            gOff[t] = (unsigned)(((jj * BB + b) * 3 + sp) * XW_PLANE)
                    + (unsigned)((s0 + sr) * 512 + oc * 16);
        } else {
            const int sl = slot - 30;
            const int p  = sl >> 1;                // plane 0..14 = i*3+sp
            const int u  = (sl & 1) * 64 + lane;
            const int sr = u >> 2;                 // o-row within tile
            const int oc = (u & 3) ^ (sr & 3) ^ ((sr >> 2) & 3);
            gOff[t] = (unsigned)W2_OFF
                    + (unsigned)((p * CC + o0 + sr) * 512 + oc * 16);
        }
    }

    // ---- A frag per-lane base (k-minor planes) ----
    const unsigned vAW = (unsigned)AW_OFF + (unsigned)(o0 + ar) * 512u + (unsigned)qd * 16u;
    // X frag LDS byte offset (within plane, swizzled)
    const unsigned xb = (unsigned)(xr * 4 + (qd ^ (xr & 3) ^ ((xr >> 2) & 3))) * 16u;
    // W2 frag LDS byte offset (within plane, swizzled; o-row = ar)
    const unsigned wb = (unsigned)(ar * 4 + (qd ^ (ar & 3) ^ ((ar >> 2) & 3))) * 16u;

    f32x4 accY[NI][NN];
    f32x4 accU[NI];
    #pragma unroll
    for (int ii = 0; ii < NI; ii++) {
        accU[ii] = (f32x4){0.f, 0.f, 0.f, 0.f};
        #pragma unroll
        for (int j = 0; j < NN; j++) accY[ii][j] = (f32x4){0.f, 0.f, 0.f, 0.f};
    }

    #pragma unroll 1
    for (int k0 = 0; k0 < CC; k0 += 32) {
        if (k0) __syncthreads();
        // X + W2 staging DMA (swizzle carried in gaddr)
        #pragma unroll
        for (int t = 0; t < 15; t++) {
            GLD16(ws + gOff[t], SB + (sbase + t) * 1024);
            gOff[t] += 64;
        }
        // A frags for this chunk (global->reg; latency folds into the barrier drain)
        short8 af[NI][3];
        #pragma unroll
        for (int ii = 0; ii < NI; ii++)
            #pragma unroll
            for (int sp = 0; sp < 3; sp++)
                af[ii][sp] = *(const short8*)(ws + vAW
                    + (unsigned)(((IB + ii) * 3 + sp) * AW_PLANE) + (unsigned)k0 * 2);
        __syncthreads();

        // j-outer: X frags read once, shared across the i-set
        #pragma unroll
        for (int j = 0; j < NN; j++) {
            const unsigned char* xp = SB + (unsigned)(j * 3) * 2048u + xb;
            const short8 x0 = *(const short8*)(xp);
            const short8 x1 = *(const short8*)(xp + 2048);
            const short8 x2 = *(const short8*)(xp + 4096);
            #pragma unroll
            for (int ii = 0; ii < NI; ii++) {
                f32x4 c = accY[ii][j];
                c = MF(af[ii][0], x0, c);
                c = MF(af[ii][0], x1, c);
                c = MF(af[ii][1], x0, c);
                c = MF(af[ii][1], x1, c);
                c = MF(af[ii][0], x2, c);
                c = MF(af[ii][2], x0, c);
                accY[ii][j] = c;
            }
            if (j >= IB && j < IB + NI) {        // compile-time on unroll index
                const int ui = j - IB;
                // W2 frags from LDS (plane i*3+sp with i == j here)
                const unsigned char* wp = SB + 30720u + (unsigned)(j * 3) * 2048u + wb;
                const short8 w0f = *(const short8*)(wp);
                const short8 w1f = *(const short8*)(wp + 2048);
                const short8 w2f = *(const short8*)(wp + 4096);
                f32x4 u = accU[ui];
                u = MF(w0f, x0, u);
                u = MF(w0f, x1, u);
                u = MF(w1f, x0, u);
                u = MF(w1f, x1, u);
                u = MF(w0f, x2, u);
                u = MF(w2f, x0, u);
                accU[ui] = u;
            }
        }
    }

    // ---------------- epilogue (C/D: col=lane&15, row=qd*4+reg) ----------------
    const int sg  = s0 + 16 * sh + m_;
    const int og0 = o0 + 16 * oh + 4 * qd;

    float xe[NN][4];
    #pragma unroll
    for (int j = 0; j < NN; j++) {
        const float* px = x + (size_t)((j * BB + b) * CC + og0) * SSP + sg;
        #pragma unroll
        for (int r = 0; r < 4; r++) xe[j][r] = px[r * SSP];
    }

    #pragma unroll
    for (int ii = 0; ii < NI; ii++) {
        const int i = IB + ii;
        #pragma unroll
        for (int r = 0; r < 4; r++) {
            const float uu = accU[ii][r] + bias[i * CC + og0 + r];
            float e[NN]; float mx = 0.f;
            #pragma unroll
            for (int j = 0; j < NN; j++) {
                float d = fabsf(xe[j][r] - (accY[ii][j][r] + uu));
                d = (d > THRESHV) ? d : 0.f;
                e[j] = d; mx = fmaxf(mx, d);
            }
            float sum = 0.f, hv = 0.f;
            #pragma unroll
            for (int j = 0; j < NN; j++) {
                const float p = __expf(e[j] - mx);
                sum += p; hv += p * xe[j][r];
            }
            out[(size_t)((i * BB + b) * CC + og0 + r) * SSP + sg] = hv / sum;
        }
    }
}

// ================= fallback (R2 kernel, self-splitting; known-good) ==========
static __device__ __forceinline__ void st4(unsigned short* p, unsigned short a,
                                           unsigned short b, unsigned short c, unsigned short d) {
    ushort4 v; v.x = a; v.y = b; v.z = c; v.w = d;
    *(ushort4*)p = v;
}
#define XB 15360
__global__ __launch_bounds__(512, 2)
void fub_mfma(const float* __restrict__ x, const float* __restrict__ w,
              const float* __restrict__ bias, float* __restrict__ out)
{
    __shared__ unsigned short S[30720];
    const int tid = threadIdx.x;
    const int b = blockIdx.z, o0 = blockIdx.y * 32, s0 = blockIdx.x * 32;
    const int lane = tid & 63, wv = tid >> 6;
    const int q = wv & 3, oh = q >> 1, sh = q & 1, iset = wv >> 2, qd = lane >> 4;
    const int sub = tid >> 8, t = tid & 255;
    const int wo = t >> 3, wkg = t & 7, xs = t & 31, xkq = t >> 5;
    const int wbase = wo * 32 + (((wkg >> 1) ^ ((wo >> 1) & 3)) << 3) + ((wkg & 1) << 2);
    const int xbase = xs * 32 + (((xkq >> 1) ^ ((xs >> 1) & 3)) << 3) + ((xkq & 1) << 2);
    const int ar = 16 * oh + (lane & 15), xr = 16 * sh + (lane & 15);
    const int asw8 = ((qd ^ ((ar >> 1) & 3)) << 3), xsw8 = ((qd ^ ((xr >> 1) & 3)) << 3);
    const int arow32 = ar * 32, xrow32 = xr * 32;
    f32x4 accY[3][5]; f32x4 accU[3];
    #pragma unroll
    for (int ii = 0; ii < 3; ii++) {
        accU[ii] = (f32x4){0.f, 0.f, 0.f, 0.f};
        #pragma unroll
        for (int j = 0; j < NN; j++) accY[ii][j] = (f32x4){0.f, 0.f, 0.f, 0.f};
    }
    float w2sav[3][4];
    #pragma unroll 1
    for (int k0 = 0; k0 < CC; k0 += 32) {
        if (k0) __syncthreads();
        #pragma unroll
        for (int rep = 0; rep < 3; rep++) {
            const int i = rep * 2 + sub;
            if (i < NN) {
                const float* gw = w + (size_t)(i * CC + o0 + wo) * (2 * CC) + k0 + wkg * 4;
                const float4 w1 = *(const float4*)gw;
                const float4 w2 = *(const float4*)(gw + CC);
                w2sav[rep][0] = w2.x; w2sav[rep][1] = w2.y; w2sav[rep][2] = w2.z; w2sav[rep][3] = w2.w;
                float av[4] = {w1.x + w2.x, w1.y + w2.y, w1.z + w2.z, w1.w + w2.w};
                unsigned short h[4], m[4], l[4];
                #pragma unroll
                for (int r = 0; r < 4; r++) split3(av[r], h[r], m[r], l[r]);
                unsigned short* p = &S[i * 3 * 1024 + wbase];
                st4(p, h[0], h[1], h[2], h[3]); st4(p + 1024, m[0], m[1], m[2], m[3]); st4(p + 2048, l[0], l[1], l[2], l[3]);
            }
        }
        #pragma unroll
        for (int rep = 0; rep < 3; rep++) {
            const int j = rep * 2 + sub;
            if (j < NN) {
                const float* gx = x + (size_t)((j * BB + b) * CC + k0 + xkq * 4) * SSP + s0 + xs;
                float v[4] = {gx[0], gx[SSP], gx[2 * SSP], gx[3 * SSP]};
                unsigned short h[4], m[4], l[4];
                #pragma unroll
                for (int r = 0; r < 4; r++) split3(v[r], h[r], m[r], l[r]);
                unsigned short* p = &S[XB + j * 3 * 1024 + xbase];
                st4(p, h[0], h[1], h[2], h[3]); st4(p + 1024, m[0], m[1], m[2], m[3]); st4(p + 2048, l[0], l[1], l[2], l[3]);
            }
        }
        __syncthreads();
        short8 xf[NN][3];
        #pragma unroll
        for (int j = 0; j < NN; j++)
            #pragma unroll
            for (int sp = 0; sp < 3; sp++)
                xf[j][sp] = *(const short8*)&S[XB + (j * 3 + sp) * 1024 + xrow32 + xsw8];
#define YPL(IB_, NI_)                                                           \
        {                                                                       \
            _Pragma("unroll")                                                   \
            for (int ii = 0; ii < NI_; ii++) {                                  \
                const int i = IB_ + ii;                                         \
                const unsigned short* ap = &S[i * 3 * 1024 + arow32 + asw8];    \
                const short8 ah = *(const short8*)(ap);                         \
                const short8 am = *(const short8*)(ap + 1024);                  \
                const short8 al = *(const short8*)(ap + 2048);                  \
                _Pragma("unroll")                                               \
                for (int j = 0; j < NN; j++) {                                  \
                    f32x4 c = accY[ii][j];                                      \
                    c = MF(ah, xf[j][0], c); c = MF(ah, xf[j][1], c);           \
                    c = MF(am, xf[j][0], c); c = MF(am, xf[j][1], c);           \
                    c = MF(ah, xf[j][2], c); c = MF(al, xf[j][0], c);           \
                    accY[ii][j] = c;                                            \
                }                                                               \
            }                                                                   \
        }
        if (iset == 0) { YPL(0, 2) } else { YPL(2, 3) }
        __syncthreads();
        #pragma unroll
        for (int rep = 0; rep < 3; rep++) {
            const int i = rep * 2 + sub;
            if (i < NN) {
                unsigned short h[4], m[4], l[4];
                #pragma unroll
                for (int r = 0; r < 4; r++) split3(w2sav[rep][r], h[r], m[r], l[r]);
                unsigned short* p = &S[i * 3 * 1024 + wbase];
                st4(p, h[0], h[1], h[2], h[3]); st4(p + 1024, m[0], m[1], m[2], m[3]); st4(p + 2048, l[0], l[1], l[2], l[3]);
            }
        }
        __syncthreads();
#define UPL(IB_, NI_)                                                           \
        {                                                                       \
            _Pragma("unroll")                                                   \
            for (int ii = 0; ii < NI_; ii++) {                                  \
                const int i = IB_ + ii;                                         \
                const unsigned short* wp = &S[i * 3 * 1024 + arow32 + asw8];    \
                const short8 wh = *(const short8*)(wp);                         \
                const short8 wm = *(const short8*)(wp + 1024);                  \
                const short8 wl = *(const short8*)(wp + 2048);                  \
                f32x4 u = accU[ii];                                             \
                u = MF(wh, xf[i][0], u); u = MF(wh, xf[i][1], u);               \
                u = MF(wm, xf[i][0], u); u = MF(wm, xf[i][1], u);               \
                u = MF(wh, xf[i][2], u); u = MF(wl, xf[i][0], u);               \
                accU[ii] = u;                                                   \
            }                                                                   \
        }
        if (iset == 0) { UPL(0, 2) } else { UPL(2, 3) }
    }
    const int sg = s0 + 16 * sh + (lane & 15);
    const int og0 = o0 + 16 * oh + 4 * qd;
    float xe[NN][4];
    #pragma unroll
    for (int j = 0; j < NN; j++) {
        const float* px = x + (size_t)((j * BB + b) * CC + og0) * SSP + sg;
        #pragma unroll
        for (int r = 0; r < 4; r++) xe[j][r] = px[r * SSP];
    }
#define EPI(IB_, NI_)                                                           \
    {                                                                           \
        _Pragma("unroll")                                                       \
        for (int ii = 0; ii < NI_; ii++) {                                      \
            const int i = IB_ + ii;                                             \
            _Pragma("unroll")                                                   \
            for (int r = 0; r < 4; r++) {                                       \
                const float uu = accU[ii][r] + bias[i * CC + og0 + r];          \
                float e[NN]; float mx = 0.f;                                    \
                _Pragma("unroll")                                               \
                for (int j = 0; j < NN; j++) {                                  \
                    float d = fabsf(xe[j][r] - (accY[ii][j][r] + uu));          \
                    d = (d > THRESHV) ? d : 0.f;                                \
                    e[j] = d; mx = fmaxf(mx, d);                                \
                }                                                               \
                float sum = 0.f, hv = 0.f;                                      \
                _Pragma("unroll")                                               \
                for (int j = 0; j < NN; j++) {                                  \
                    const float p = __expf(e[j] - mx);                          \
                    sum += p; hv += p * xe[j][r];                               \
                }                                                               \
                out[(size_t)((i * BB + b) * CC + og0 + r) * SSP + sg] = hv / sum; \
            }                                                                   \
        }                                                                       \
    }
    if (iset == 0) { EPI(0, 2) } else { EPI(2, 3) }
}

extern "C" void kernel_launch(void* const* d_in, const int* in_sizes, int n_in,
                              void* d_out, int out_size, void* d_ws, size_t ws_size,
                              hipStream_t stream) {
    const float* x      = (const float*)d_in[0];
    const float* conv_w = (const float*)d_in[1];
    const float* conv_b = (const float*)d_in[2];
    float* out = (float*)d_out;

    if (ws_size >= WS_NEED) {
        unsigned char* ws = (unsigned char*)d_ws;
        prep_all<<<2720, 256, 0, stream>>>(x, conv_w, ws);
        dim3 grid(SSP / 32, CC / 32, BB);   // 2048 blocks, all 5 i fused
        fub_main<0, 5><<<grid, 256, 0, stream>>>(x, conv_b, ws, out);
    } else {
        fub_mfma<<<dim3(SSP / 32, CC / 32, BB), 512, 0, stream>>>(x, conv_w, conv_b, out);
    }
}

// Round 10
// 271.640 us; speedup vs baseline: 1.9314x; 1.0547x over previous
//
#include <hip/hip_runtime.h>
#include <math.h>

// N=5, B=8, C=256, H*W=1024
#define NN 5
#define CC 256
#define SSP 1024
#define BB 8
#define THRESHV 0.3f

typedef __attribute__((ext_vector_type(8))) short short8;   // 8 bf16 = one MFMA A/B frag
typedef __attribute__((ext_vector_type(4))) float f32x4;    // MFMA 16x16 accumulator

// ---------------- ws layout (bytes) ----------------
// X split planes, k-minor: [(j*8+b)*3+sp][s:1024][k:256] bf16
#define XW_OFF   0ull
#define XW_PLANE ((size_t)SSP * CC * 2)                 // 524288
#define XW_SIZE  ((size_t)NN * BB * 3 * XW_PLANE)       // 62,914,560
// A = W1+W2 split planes, k-minor: [i*3+sp][o:256][k:256]
#define AW_OFF   XW_SIZE
#define AW_PLANE ((size_t)CC * CC * 2)                  // 131072
#define AW_SIZE  ((size_t)NN * 3 * AW_PLANE)            // 1,966,080
#define W2_OFF   (AW_OFF + AW_SIZE)
#define WS_NEED  (W2_OFF + AW_SIZE)                     // ~63.8 MiB

// ---- exact 3-way bf16 split (Dekker-style; residuals exact in fp32) ----
static __device__ __forceinline__ unsigned short f2bf(float f) {
    unsigned int u = __builtin_bit_cast(unsigned int, f);
    u = u + 0x7fffu + ((u >> 16) & 1u);          // RNE to bf16
    return (unsigned short)(u >> 16);
}
static __device__ __forceinline__ float bf2f(unsigned short h) {
    unsigned int u = ((unsigned int)h) << 16;
    return __builtin_bit_cast(float, u);
}
static __device__ __forceinline__ void split3(float a, unsigned short& h,
                                              unsigned short& m, unsigned short& l) {
    h = f2bf(a); float r1 = a - bf2f(h);
    m = f2bf(r1); float r2 = r1 - bf2f(m);
    l = f2bf(r2);
}
static __device__ __forceinline__ f32x4 MF(short8 a, short8 b, f32x4 c) {
    return __builtin_amdgcn_mfma_f32_16x16x32_bf16(a, b, c, 0, 0, 0);
}

// async global->LDS, 16B per lane; LDS dest = uniform base + lane*16
#define GLD16(gp, lp) __builtin_amdgcn_global_load_lds(                          \
        (const __attribute__((address_space(1))) unsigned int*)(gp),             \
        (__attribute__((address_space(3))) unsigned int*)(lp), 16, 0, 0)

// ================= merged pre-pass (R9 version, ~20-25us) =================
// Blocks 0..2559 : X split+transpose via LDS, ONE (jb,kc,sc) 128-row tile per
//   block (30720B LDS -> 5 blocks/CU). Blocks 2560..2719: weight split.
#define PXS 40
__global__ __launch_bounds__(256)
void prep_all(const float* __restrict__ x, const float* __restrict__ w,
              unsigned char* __restrict__ ws) {
    __shared__ unsigned short S[3 * 128 * PXS];      // 30720 B
    const int tid = threadIdx.x;

    if (blockIdx.x >= 2560) {
        // ---------------- weight split (verbatim math) ----------------------
        const int id = (blockIdx.x - 2560) * 256 + tid;  // 40960 = 5*256*32
        const int i  = id >> 13;
        const int o  = (id >> 5) & 255;
        const int ko = id & 31;                          // k-oct
        const float* gw = w + (size_t)(i * CC + o) * (2 * CC) + ko * 8;
        float av[8], wv[8];
        #pragma unroll
        for (int kk = 0; kk < 8; kk++) {
            wv[kk] = gw[CC + kk];
            av[kk] = gw[kk] + wv[kk];
        }
        unsigned short h[8], m[8], l[8];
        short8 H, M, L;
        #pragma unroll
        for (int kk = 0; kk < 8; kk++) split3(av[kk], h[kk], m[kk], l[kk]);
        #pragma unroll
        for (int kk = 0; kk < 8; kk++) { H[kk] = (short)h[kk]; M[kk] = (short)m[kk]; L[kk] = (short)l[kk]; }
        {
            unsigned char* p = ws + AW_OFF + (size_t)((i * 3) * CC + o) * 512 + ko * 16;
            *(short8*)(p)                = H;
            *(short8*)(p + CC * 512)     = M;
            *(short8*)(p + 2 * CC * 512) = L;
        }
        #pragma unroll
        for (int kk = 0; kk < 8; kk++) split3(wv[kk], h[kk], m[kk], l[kk]);
        #pragma unroll
        for (int kk = 0; kk < 8; kk++) { H[kk] = (short)h[kk]; M[kk] = (short)m[kk]; L[kk] = (short)l[kk]; }
        {
            unsigned char* p = ws + W2_OFF + (size_t)((i * 3) * CC + o) * 512 + ko * 16;
            *(short8*)(p)                = H;
            *(short8*)(p + CC * 512)     = M;
            *(short8*)(p + 2 * CC * 512) = L;
        }
        return;
    }

    // ---------------- X split + transpose (blocks 0..2559) ------------------
    const int blk = blockIdx.x;          // 2560 = 40 jb * 8 kc * 8 sc
    const int sc  = blk & 7;             // 128-row tile index
    const int kc  = (blk >> 3) & 7;
    const int jb  = blk >> 6;            // j*8+b
    const int k0  = kc * 32;
    unsigned char* const pl0 = ws + XW_OFF + (size_t)(jb * 3) * XW_PLANE
                             + (size_t)(k0 * 2);

    const int s   = tid & 127;           // row within tile
    const int kh  = tid >> 7;            // 0/1: 16-k half of the 32-k chunk
    const int swk = (s & 3) ^ ((s >> 3) & 3);     // row swizzle key

    const float* gx = x + ((size_t)jb * CC + k0 + kh * 16) * SSP + sc * 128 + s;
    // read coalesced (256B/instr per wave), split, stage in LDS
    #pragma unroll
    for (int lp = 0; lp < 8; lp++) {             // pairs of k within this half
        const float v0 = gx[(size_t)(2 * lp) * SSP];
        const float v1 = gx[(size_t)(2 * lp + 1) * SSP];
        unsigned short h0, m0, l0, h1, m1, l1;
        split3(v0, h0, m0, l0);
        split3(v1, h1, m1, l1);
        const int gp  = kh * 8 + lp;              // global k-pair 0..15
        const int po  = (gp >> 2) ^ swk;          // swizzled 16B unit
        const int idx = s * PXS + po * 8 + (gp & 3) * 2;
        *(unsigned int*)&S[idx]             = (unsigned)h0 | ((unsigned)h1 << 16);
        *(unsigned int*)&S[idx + 128 * PXS] = (unsigned)m0 | ((unsigned)m1 << 16);
        *(unsigned int*)&S[idx + 256 * PXS] = (unsigned)l0 | ((unsigned)l1 << 16);
    }
    __syncthreads();
    // write out transposed: 4 lanes cover one 64B s-row segment
    #pragma unroll
    for (int sp = 0; sp < 3; sp++) {
        #pragma unroll
        for (int it = 0; it < 2; it++) {
            const int u   = it * 256 + tid;       // 0..511
            const int su  = u >> 2, ko = u & 3;
            const int pko = ko ^ (su & 3) ^ ((su >> 3) & 3);
            const short8 v = *(const short8*)&S[sp * 128 * PXS + su * PXS + pko * 8];
            *(short8*)(pl0 + (size_t)sp * XW_PLANE
                       + (size_t)(sc * 128 + su) * 512 + ko * 16) = v;
        }
    }
}

// ================= main fused kernel (R2 structure + A-hm staged) ============
// LDS (81920 B; 2 blocks = exactly 160 KiB/CU, proven co-resident in R4):
//   [0,30720)      X planes   (15 x 2KB, j*3+sp)
//   [30720,61440)  W2 planes  (15 x 2KB, i*3+sp)
//   [61440,81920)  A h/m      (10 x 2KB, i*2+sp)   <- NEW: was wave-duplicated
//                                                      global->reg (waves 0/1,
//                                                      2/3 loaded identical
//                                                      rows; 60KB requests ->
//                                                      20KB staged + 20KB A-l)
// 80 GLD16 slots per chunk = 20 per wave; A-l (5 frags) stays global->reg
// pre-barrier. Same products, same accumulation order -> bit-exact.
// NOTE (R3-R6): dbuf/counted-vmcnt/phase/all-register variants all lost to
// this plain 2-barrier loop; ~248/512 regs pins 2 waves/SIMD, cross-block
// drift is the latency-hiding mechanism. Do not re-pipeline.
template<int IB, int NI>
__global__ __launch_bounds__(256, 2)
void fub_main(const float* __restrict__ x, const float* __restrict__ bias,
              const unsigned char* __restrict__ ws, float* __restrict__ out)
{
    __shared__ unsigned char SB[81920];

    const int tid  = threadIdx.x;
    const int b    = blockIdx.z;
    const int o0   = blockIdx.y * 32;
    const int s0   = blockIdx.x * 32;
    const int lane = tid & 63;
    const int w    = tid >> 6;            // wave 0..3 -> tile quarter
    const int oh   = w >> 1, sh = w & 1;
    const int qd   = lane >> 4;
    const int m_   = lane & 15;
    const int ar   = 16 * oh + m_;        // o row for A/W2 frags
    const int xr   = 16 * sh + m_;        // s row for X frags

    // ---- DMA staging: 80 slots over 4 waves (20 each) ----
    // slots 0..29 : X planes  (p = slot>>1 = j*3+sp), rows are s-rows
    // slots 30..59: W2 planes (p = (slot-30)>>1 = i*3+sp), rows are o-rows
    // slots 60..79: A h/m     (p = (slot-60)>>1 = i*2+sp, sp in {0,1}), o-rows
    const int sbase = w * 20;
    unsigned gOff[20];
    #pragma unroll
    for (int t = 0; t < 20; t++) {
        const int slot = sbase + t;
        if (slot < 30) {
            const int p  = slot >> 1;              // plane 0..14 = j*3+sp
            const int jj = p / 3, sp = p - 3 * jj;
            const int u  = (slot & 1) * 64 + lane; // unit within plane
            const int sr = u >> 2;
            const int oc = (u & 3) ^ (sr & 3) ^ ((sr >> 2) & 3);
            gOff[t] = (unsigned)(((jj * BB + b) * 3 + sp) * XW_PLANE)
                    + (unsigned)((s0 + sr) * 512 + oc * 16);
        } else if (slot < 60) {
            const int sl = slot - 30;
            const int p  = sl >> 1;                // plane 0..14 = i*3+sp
            const int u  = (sl & 1) * 64 + lane;
            const int sr = u >> 2;                 // o-row within tile
            const int oc = (u & 3) ^ (sr & 3) ^ ((sr >> 2) & 3);
            gOff[t] = (unsigned)W2_OFF
                    + (unsigned)((p * CC + o0 + sr) * 512 + oc * 16);
        } else {
            const int sl = slot - 60;
            const int p  = sl >> 1;                // 0..9 = i*2+sp (sp in {0,1})
            const int i_ = p >> 1, sp = p & 1;
            const int u  = (sl & 1) * 64 + lane;
            const int sr = u >> 2;                 // o-row within tile
            const int oc = (u & 3) ^ (sr & 3) ^ ((sr >> 2) & 3);
            gOff[t] = (unsigned)AW_OFF
                    + (unsigned)(((i_ * 3 + sp) * CC + o0 + sr) * 512 + oc * 16);
        }
    }

    // ---- A-l frag per-lane base (k-minor planes; h/m come from LDS now) ----
    const unsigned vAW = (unsigned)AW_OFF + (unsigned)(o0 + ar) * 512u + (unsigned)qd * 16u;
    // X frag LDS byte offset (within plane, swizzled)
    const unsigned xb = (unsigned)(xr * 4 + (qd ^ (xr & 3) ^ ((xr >> 2) & 3))) * 16u;
    // W2/A frag LDS byte offset (within plane, swizzled; o-row = ar)
    const unsigned wb = (unsigned)(ar * 4 + (qd ^ (ar & 3) ^ ((ar >> 2) & 3))) * 16u;

    f32x4 accY[NI][NN];
    f32x4 accU[NI];
    #pragma unroll
    for (int ii = 0; ii < NI; ii++) {
        accU[ii] = (f32x4){0.f, 0.f, 0.f, 0.f};
        #pragma unroll
        for (int j = 0; j < NN; j++) accY[ii][j] = (f32x4){0.f, 0.f, 0.f, 0.f};
    }

    #pragma unroll 1
    for (int k0 = 0; k0 < CC; k0 += 32) {
        if (k0) __syncthreads();
        // X + W2 + A-hm staging DMA (swizzle carried in gaddr)
        #pragma unroll
        for (int t = 0; t < 20; t++) {
            GLD16(ws + gOff[t], SB + (sbase + t) * 1024);
            gOff[t] += 64;
        }
        // A-l frags for this chunk (global->reg; latency folds into the drain)
        short8 af[NI][3];
        #pragma unroll
        for (int ii = 0; ii < NI; ii++)
            af[ii][2] = *(const short8*)(ws + vAW
                + (unsigned)(((IB + ii) * 3 + 2) * AW_PLANE) + (unsigned)k0 * 2);
        __syncthreads();

        // A h/m frags from LDS (plane i*2+sp)
        #pragma unroll
        for (int ii = 0; ii < NI; ii++) {
            const unsigned char* ap = SB + 61440u + (unsigned)((IB + ii) * 2) * 2048u + wb;
            af[ii][0] = *(const short8*)(ap);
            af[ii][1] = *(const short8*)(ap + 2048);
        }

        // j-outer: X frags read once, shared across the i-set
        #pragma unroll
        for (int j = 0; j < NN; j++) {
            const unsigned char* xp = SB + (unsigned)(j * 3) * 2048u + xb;
            const short8 x0 = *(const short8*)(xp);
            const short8 x1 = *(const short8*)(xp + 2048);
            const short8 x2 = *(const short8*)(xp + 4096);
            #pragma unroll
            for (int ii = 0; ii < NI; ii++) {
                f32x4 c = accY[ii][j];
                c = MF(af[ii][0], x0, c);
                c = MF(af[ii][0], x1, c);
                c = MF(af[ii][1], x0, c);
                c = MF(af[ii][1], x1, c);
                c = MF(af[ii][0], x2, c);
                c = MF(af[ii][2], x0, c);
                accY[ii][j] = c;
            }
            if (j >= IB && j < IB + NI) {        // compile-time on unroll index
                const int ui = j - IB;
                // W2 frags from LDS (plane i*3+sp with i == j here)
                const unsigned char* wp = SB + 30720u + (unsigned)(j * 3) * 2048u + wb;
                const short8 w0f = *(const short8*)(wp);
                const short8 w1f = *(const short8*)(wp + 2048);
                const short8 w2f = *(const short8*)(wp + 4096);
                f32x4 u = accU[ui];
                u = MF(w0f, x0, u);
                u = MF(w0f, x1, u);
                u = MF(w1f, x0, u);
                u = MF(w1f, x1, u);
                u = MF(w0f, x2, u);
                u = MF(w2f, x0, u);
                accU[ui] = u;
            }
        }
    }

    // ---------------- epilogue (C/D: col=lane&15, row=qd*4+reg) ----------------
    const int sg  = s0 + 16 * sh + m_;
    const int og0 = o0 + 16 * oh + 4 * qd;

    float xe[NN][4];
    #pragma unroll
    for (int j = 0; j < NN; j++) {
        const float* px = x + (size_t)((j * BB + b) * CC + og0) * SSP + sg;
        #pragma unroll
        for (int r = 0; r < 4; r++) xe[j][r] = px[r * SSP];
    }

    #pragma unroll
    for (int ii = 0; ii < NI; ii++) {
        const int i = IB + ii;
        #pragma unroll
        for (int r = 0; r < 4; r++) {
            const float uu = accU[ii][r] + bias[i * CC + og0 + r];
            float e[NN]; float mx = 0.f;
            #pragma unroll
            for (int j = 0; j < NN; j++) {
                float d = fabsf(xe[j][r] - (accY[ii][j][r] + uu));
                d = (d > THRESHV) ? d : 0.f;
                e[j] = d; mx = fmaxf(mx, d);
            }
            float sum = 0.f, hv = 0.f;
            #pragma unroll
            for (int j = 0; j < NN; j++) {
                const float p = __expf(e[j] - mx);
                sum += p; hv += p * xe[j][r];
            }
            out[(size_t)((i * BB + b) * CC + og0 + r) * SSP + sg] = hv / sum;
        }
    }
}

// ================= fallback (R2 kernel, self-splitting; known-good) ==========
static __device__ __forceinline__ void st4(unsigned short* p, unsigned short a,
                                           unsigned short b, unsigned short c, unsigned short d) {
    ushort4 v; v.x = a; v.y = b; v.z = c; v.w = d;
    *(ushort4*)p = v;
}
#define XB 15360
__global__ __launch_bounds__(512, 2)
void fub_mfma(const float* __restrict__ x, const float* __restrict__ w,
              const float* __restrict__ bias, float* __restrict__ out)
{
    __shared__ unsigned short S[30720];
    const int tid = threadIdx.x;
    const int b = blockIdx.z, o0 = blockIdx.y * 32, s0 = blockIdx.x * 32;
    const int lane = tid & 63, wv = tid >> 6;
    const int q = wv & 3, oh = q >> 1, sh = q & 1, iset = wv >> 2, qd = lane >> 4;
    const int sub = tid >> 8, t = tid & 255;
    const int wo = t >> 3, wkg = t & 7, xs = t & 31, xkq = t >> 5;
    const int wbase = wo * 32 + (((wkg >> 1) ^ ((wo >> 1) & 3)) << 3) + ((wkg & 1) << 2);
    const int xbase = xs * 32 + (((xkq >> 1) ^ ((xs >> 1) & 3)) << 3) + ((xkq & 1) << 2);
    const int ar = 16 * oh + (lane & 15), xr = 16 * sh + (lane & 15);
    const int asw8 = ((qd ^ ((ar >> 1) & 3)) << 3), xsw8 = ((qd ^ ((xr >> 1) & 3)) << 3);
    const int arow32 = ar * 32, xrow32 = xr * 32;
    f32x4 accY[3][5]; f32x4 accU[3];
    #pragma unroll
    for (int ii = 0; ii < 3; ii++) {
        accU[ii] = (f32x4){0.f, 0.f, 0.f, 0.f};
        #pragma unroll
        for (int j = 0; j < NN; j++) accY[ii][j] = (f32x4){0.f, 0.f, 0.f, 0.f};
    }
    float w2sav[3][4];
    #pragma unroll 1
    for (int k0 = 0; k0 < CC; k0 += 32) {
        if (k0) __syncthreads();
        #pragma unroll
        for (int rep = 0; rep < 3; rep++) {
            const int i = rep * 2 + sub;
            if (i < NN) {
                const float* gw = w + (size_t)(i * CC + o0 + wo) * (2 * CC) + k0 + wkg * 4;
                const float4 w1 = *(const float4*)gw;
                const float4 w2 = *(const float4*)(gw + CC);
                w2sav[rep][0] = w2.x; w2sav[rep][1] = w2.y; w2sav[rep][2] = w2.z; w2sav[rep][3] = w2.w;
                float av[4] = {w1.x + w2.x, w1.y + w2.y, w1.z + w2.z, w1.w + w2.w};
                unsigned short h[4], m[4], l[4];
                #pragma unroll
                for (int r = 0; r < 4; r++) split3(av[r], h[r], m[r], l[r]);
                unsigned short* p = &S[i * 3 * 1024 + wbase];
                st4(p, h[0], h[1], h[2], h[3]); st4(p + 1024, m[0], m[1], m[2], m[3]); st4(p + 2048, l[0], l[1], l[2], l[3]);
            }
        }
        #pragma unroll
        for (int rep = 0; rep < 3; rep++) {
            const int j = rep * 2 + sub;
            if (j < NN) {
                const float* gx = x + (size_t)((j * BB + b) * CC + k0 + xkq * 4) * SSP + s0 + xs;
                float v[4] = {gx[0], gx[SSP], gx[2 * SSP], gx[3 * SSP]};
                unsigned short h[4], m[4], l[4];
                #pragma unroll
                for (int r = 0; r < 4; r++) split3(v[r], h[r], m[r], l[r]);
                unsigned short* p = &S[XB + j * 3 * 1024 + xbase];
                st4(p, h[0], h[1], h[2], h[3]); st4(p + 1024, m[0], m[1], m[2], m[3]); st4(p + 2048, l[0], l[1], l[2], l[3]);
            }
        }
        __syncthreads();
        short8 xf[NN][3];
        #pragma unroll
        for (int j = 0; j < NN; j++)
            #pragma unroll
            for (int sp = 0; sp < 3; sp++)
                xf[j][sp] = *(const short8*)&S[XB + (j * 3 + sp) * 1024 + xrow32 + xsw8];
#define YPL(IB_, NI_)                                                           \
        {                                                                       \
            _Pragma("unroll")                                                   \
            for (int ii = 0; ii < NI_; ii++) {                                  \
                const int i = IB_ + ii;                                         \
                const unsigned short* ap = &S[i * 3 * 1024 + arow32 + asw8];    \
                const short8 ah = *(const short8*)(ap);                         \
                const short8 am = *(const short8*)(ap + 1024);                  \
                const short8 al = *(const short8*)(ap + 2048);                  \
                _Pragma("unroll")                                               \
                for (int j = 0; j < NN; j++) {                                  \
                    f32x4 c = accY[ii][j];                                      \
                    c = MF(ah, xf[j][0], c); c = MF(ah, xf[j][1], c);           \
                    c = MF(am, xf[j][0], c); c = MF(am, xf[j][1], c);           \
                    c = MF(ah, xf[j][2], c); c = MF(al, xf[j][0], c);           \
                    accY[ii][j] = c;                                            \
                }                                                               \
            }                                                                   \
        }
        if (iset == 0) { YPL(0, 2) } else { YPL(2, 3) }
        __syncthreads();
        #pragma unroll
        for (int rep = 0; rep < 3; rep++) {
            const int i = rep * 2 + sub;
            if (i < NN) {
                unsigned short h[4], m[4], l[4];
                #pragma unroll
                for (int r = 0; r < 4; r++) split3(w2sav[rep][r], h[r], m[r], l[r]);
                unsigned short* p = &S[i * 3 * 1024 + wbase];
                st4(p, h[0], h[1], h[2], h[3]); st4(p + 1024, m[0], m[1], m[2], m[3]); st4(p + 2048, l[0], l[1], l[2], l[3]);
            }
        }
        __syncthreads();
#define UPL(IB_, NI_)                                                           \
        {                                                                       \
            _Pragma("unroll")                                                   \
            for (int ii = 0; ii < NI_; ii++) {                                  \
                const int i = IB_ + ii;                                         \
                const unsigned short* wp = &S[i * 3 * 1024 + arow32 + asw8];    \
                const short8 wh = *(const short8*)(wp);                         \
                const short8 wm = *(const short8*)(wp + 1024);                  \
                const short8 wl = *(const short8*)(wp + 2048);                  \
                f32x4 u = accU[ii];                                             \
                u = MF(wh, xf[i][0], u); u = MF(wh, xf[i][1], u);               \
                u = MF(wm, xf[i][0], u); u = MF(wm, xf[i][1], u);               \
                u = MF(wh, xf[i][2], u); u = MF(wl, xf[i][0], u);               \
                accU[ii] = u;                                                   \
            }                                                                   \
        }
        if (iset == 0) { UPL(0, 2) } else { UPL(2, 3) }
    }
    const int sg = s0 + 16 * sh + (lane & 15);
    const int og0 = o0 + 16 * oh + 4 * qd;
    float xe[NN][4];
    #pragma unroll
    for (int j = 0; j < NN; j++) {
        const float* px = x + (size_t)((j * BB + b) * CC + og0) * SSP + sg;
        #pragma unroll
        for (int r = 0; r < 4; r++) xe[j][r] = px[r * SSP];
    }
#define EPI(IB_, NI_)                                                           \
    {                                                                           \
        _Pragma("unroll")                                                       \
        for (int ii = 0; ii < NI_; ii++) {                                      \
            const int i = IB_ + ii;                                             \
            _Pragma("unroll")                                                   \
            for (int r = 0; r < 4; r++) {                                       \
                const float uu = accU[ii][r] + bias[i * CC + og0 + r];          \
                float e[NN]; float mx = 0.f;                                    \
                _Pragma("unroll")                                               \
                for (int j = 0; j < NN; j++) {                                  \
                    float d = fabsf(xe[j][r] - (accY[ii][j][r] + uu));          \
                    d = (d > THRESHV) ? d : 0.f;                                \
                    e[j] = d; mx = fmaxf(mx, d);                                \
                }                                                               \
                float sum = 0.f, hv = 0.f;                                      \
                _Pragma("unroll")                                               \
                for (int j = 0; j < NN; j++) {                                  \
                    const float p = __expf(e[j] - mx);                          \
                    sum += p; hv += p * xe[j][r];                               \
                }                                                               \
                out[(size_t)((i * BB + b) * CC + og0 + r) * SSP + sg] = hv / sum; \
            }                                                                   \
        }                                                                       \
    }
    if (iset == 0) { EPI(0, 2) } else { EPI(2, 3) }
}

extern "C" void kernel_launch(void* const* d_in, const int* in_sizes, int n_in,
                              void* d_out, int out_size, void* d_ws, size_t ws_size,
                              hipStream_t stream) {
    const float* x      = (const float*)d_in[0];
    const float* conv_w = (const float*)d_in[1];
    const float* conv_b = (const float*)d_in[2];
    float* out = (float*)d_out;

    if (ws_size >= WS_NEED) {
        unsigned char* ws = (unsigned char*)d_ws;
        prep_all<<<2720, 256, 0, stream>>>(x, conv_w, ws);
        dim3 grid(SSP / 32, CC / 32, BB);   // 2048 blocks, all 5 i fused
        fub_main<0, 5><<<grid, 256, 0, stream>>>(x, conv_b, ws, out);
    } else {
        fub_mfma<<<dim3(SSP / 32, CC / 32, BB), 512, 0, stream>>>(x, conv_w, conv_b, out);
    }
}

// Round 11
// 251.249 us; speedup vs baseline: 2.0881x; 1.0812x over previous
//
#include <hip/hip_runtime.h>
#include <math.h>

// N=5, B=8, C=256, H*W=1024
#define NN 5
#define CC 256
#define SSP 1024
#define BB 8
#define THRESHV 0.3f

typedef __attribute__((ext_vector_type(8))) short short8;   // 8 bf16 = one MFMA A/B frag
typedef __attribute__((ext_vector_type(4))) float f32x4;    // MFMA 16x16 accumulator

// ---------------- ws layout (bytes) ----------------
// X split planes, k-minor: [(j*8+b)*3+sp][s:1024][k:256] bf16
#define XW_OFF   0ull
#define XW_PLANE ((size_t)SSP * CC * 2)                 // 524288
#define XW_SIZE  ((size_t)NN * BB * 3 * XW_PLANE)       // 62,914,560
// A = W1+W2 split planes, k-minor: [i*3+sp][o:256][k:256]
#define AW_OFF   XW_SIZE
#define AW_PLANE ((size_t)CC * CC * 2)                  // 131072
#define AW_SIZE  ((size_t)NN * 3 * AW_PLANE)            // 1,966,080
#define W2_OFF   (AW_OFF + AW_SIZE)
#define WS_NEED  (W2_OFF + AW_SIZE)                     // ~63.8 MiB

// ---- exact 3-way bf16 split (Dekker-style; residuals exact in fp32) ----
static __device__ __forceinline__ unsigned short f2bf(float f) {
    unsigned int u = __builtin_bit_cast(unsigned int, f);
    u = u + 0x7fffu + ((u >> 16) & 1u);          // RNE to bf16
    return (unsigned short)(u >> 16);
}
static __device__ __forceinline__ float bf2f(unsigned short h) {
    unsigned int u = ((unsigned int)h) << 16;
    return __builtin_bit_cast(float, u);
}
static __device__ __forceinline__ void split3(float a, unsigned short& h,
                                              unsigned short& m, unsigned short& l) {
    h = f2bf(a); float r1 = a - bf2f(h);
    m = f2bf(r1); float r2 = r1 - bf2f(m);
    l = f2bf(r2);
}
static __device__ __forceinline__ f32x4 MF(short8 a, short8 b, f32x4 c) {
    return __builtin_amdgcn_mfma_f32_16x16x32_bf16(a, b, c, 0, 0, 0);
}

// async global->LDS, 16B per lane; LDS dest = uniform base + lane*16
#define GLD16(gp, lp) __builtin_amdgcn_global_load_lds(                          \
        (const __attribute__((address_space(1))) unsigned int*)(gp),             \
        (__attribute__((address_space(3))) unsigned int*)(lp), 16, 0, 0)

// ================= merged pre-pass (R9 version, ~20-25us) =================
// Blocks 0..2559 : X split+transpose via LDS, ONE (jb,kc,sc) 128-row tile per
//   block (30720B LDS -> 5 blocks/CU). Blocks 2560..2719: weight split.
#define PXS 40
__global__ __launch_bounds__(256)
void prep_all(const float* __restrict__ x, const float* __restrict__ w,
              unsigned char* __restrict__ ws) {
    __shared__ unsigned short S[3 * 128 * PXS];      // 30720 B
    const int tid = threadIdx.x;

    if (blockIdx.x >= 2560) {
        // ---------------- weight split (verbatim math) ----------------------
        const int id = (blockIdx.x - 2560) * 256 + tid;  // 40960 = 5*256*32
        const int i  = id >> 13;
        const int o  = (id >> 5) & 255;
        const int ko = id & 31;                          // k-oct
        const float* gw = w + (size_t)(i * CC + o) * (2 * CC) + ko * 8;
        float av[8], wv[8];
        #pragma unroll
        for (int kk = 0; kk < 8; kk++) {
            wv[kk] = gw[CC + kk];
            av[kk] = gw[kk] + wv[kk];
        }
        unsigned short h[8], m[8], l[8];
        short8 H, M, L;
        #pragma unroll
        for (int kk = 0; kk < 8; kk++) split3(av[kk], h[kk], m[kk], l[kk]);
        #pragma unroll
        for (int kk = 0; kk < 8; kk++) { H[kk] = (short)h[kk]; M[kk] = (short)m[kk]; L[kk] = (short)l[kk]; }
        {
            unsigned char* p = ws + AW_OFF + (size_t)((i * 3) * CC + o) * 512 + ko * 16;
            *(short8*)(p)                = H;
            *(short8*)(p + CC * 512)     = M;
            *(short8*)(p + 2 * CC * 512) = L;
        }
        #pragma unroll
        for (int kk = 0; kk < 8; kk++) split3(wv[kk], h[kk], m[kk], l[kk]);
        #pragma unroll
        for (int kk = 0; kk < 8; kk++) { H[kk] = (short)h[kk]; M[kk] = (short)m[kk]; L[kk] = (short)l[kk]; }
        {
            unsigned char* p = ws + W2_OFF + (size_t)((i * 3) * CC + o) * 512 + ko * 16;
            *(short8*)(p)                = H;
            *(short8*)(p + CC * 512)     = M;
            *(short8*)(p + 2 * CC * 512) = L;
        }
        return;
    }

    // ---------------- X split + transpose (blocks 0..2559) ------------------
    const int blk = blockIdx.x;          // 2560 = 40 jb * 8 kc * 8 sc
    const int sc  = blk & 7;             // 128-row tile index
    const int kc  = (blk >> 3) & 7;
    const int jb  = blk >> 6;            // j*8+b
    const int k0  = kc * 32;
    unsigned char* const pl0 = ws + XW_OFF + (size_t)(jb * 3) * XW_PLANE
                             + (size_t)(k0 * 2);

    const int s   = tid & 127;           // row within tile
    const int kh  = tid >> 7;            // 0/1: 16-k half of the 32-k chunk
    const int swk = (s & 3) ^ ((s >> 3) & 3);     // row swizzle key

    const float* gx = x + ((size_t)jb * CC + k0 + kh * 16) * SSP + sc * 128 + s;
    // read coalesced (256B/instr per wave), split, stage in LDS
    #pragma unroll
    for (int lp = 0; lp < 8; lp++) {             // pairs of k within this half
        const float v0 = gx[(size_t)(2 * lp) * SSP];
        const float v1 = gx[(size_t)(2 * lp + 1) * SSP];
        unsigned short h0, m0, l0, h1, m1, l1;
        split3(v0, h0, m0, l0);
        split3(v1, h1, m1, l1);
        const int gp  = kh * 8 + lp;              // global k-pair 0..15
        const int po  = (gp >> 2) ^ swk;          // swizzled 16B unit
        const int idx = s * PXS + po * 8 + (gp & 3) * 2;
        *(unsigned int*)&S[idx]             = (unsigned)h0 | ((unsigned)h1 << 16);
        *(unsigned int*)&S[idx + 128 * PXS] = (unsigned)m0 | ((unsigned)m1 << 16);
        *(unsigned int*)&S[idx + 256 * PXS] = (unsigned)l0 | ((unsigned)l1 << 16);
    }
    __syncthreads();
    // write out transposed: 4 lanes cover one 64B s-row segment
    #pragma unroll
    for (int sp = 0; sp < 3; sp++) {
        #pragma unroll
        for (int it = 0; it < 2; it++) {
            const int u   = it * 256 + tid;       // 0..511
            const int su  = u >> 2, ko = u & 3;
            const int pko = ko ^ (su & 3) ^ ((su >> 3) & 3);
            const short8 v = *(const short8*)&S[sp * 128 * PXS + su * PXS + pko * 8];
            *(short8*)(pl0 + (size_t)sp * XW_PLANE
                       + (size_t)(sc * 128 + su) * 512 + ko * 16) = v;
        }
    }
}

// ================= main fused kernel (R10 structure, 5-product split) ========
// LDS (81920 B; 2 blocks = exactly 160 KiB/CU, co-resident):
//   [0,30720)      X planes   (15 x 2KB, j*3+sp)
//   [30720,61440)  W2 planes  (15 x 2KB, i*3+sp)
//   [61440,81920)  A h/m      (10 x 2KB, i*2+sp)
// 80 GLD16 slots per chunk = 20 per wave; A-l (5 frags) global->reg pre-barrier.
// R11 change: the m*m cross product (Am*Xm / W2m*Xm) is DROPPED: its magnitude
// is ~2^-16 relative, the same order as the already-dropped m*l/l*m/l*l terms.
// 6 -> 5 MFMA per product term (180 -> 150 per wave-chunk, -17% MFMA work).
// Error budget ~1e-5 absolute on O(1) Y; absmax moves off 0.05078125 (threshold
// flips change) but stays in the same ~0.05 flip-signature band.
// NOTE (R3-R6): dbuf/counted-vmcnt/phase/all-register variants all lost to
// this plain 2-barrier loop; ~248/512 regs pins 2 waves/SIMD, cross-block
// drift is the latency-hiding mechanism. Do not re-pipeline.
template<int IB, int NI>
__global__ __launch_bounds__(256, 2)
void fub_main(const float* __restrict__ x, const float* __restrict__ bias,
              const unsigned char* __restrict__ ws, float* __restrict__ out)
{
    __shared__ unsigned char SB[81920];

    const int tid  = threadIdx.x;
    const int b    = blockIdx.z;
    const int o0   = blockIdx.y * 32;
    const int s0   = blockIdx.x * 32;
    const int lane = tid & 63;
    const int w    = tid >> 6;            // wave 0..3 -> tile quarter
    const int oh   = w >> 1, sh = w & 1;
    const int qd   = lane >> 4;
    const int m_   = lane & 15;
    const int ar   = 16 * oh + m_;        // o row for A/W2 frags
    const int xr   = 16 * sh + m_;        // s row for X frags

    // ---- DMA staging: 80 slots over 4 waves (20 each) ----
    // slots 0..29 : X planes  (p = slot>>1 = j*3+sp), rows are s-rows
    // slots 30..59: W2 planes (p = (slot-30)>>1 = i*3+sp), rows are o-rows
    // slots 60..79: A h/m     (p = (slot-60)>>1 = i*2+sp, sp in {0,1}), o-rows
    const int sbase = w * 20;
    unsigned gOff[20];
    #pragma unroll
    for (int t = 0; t < 20; t++) {
        const int slot = sbase + t;
        if (slot < 30) {
            const int p  = slot >> 1;              // plane 0..14 = j*3+sp
            const int jj = p / 3, sp = p - 3 * jj;
            const int u  = (slot & 1) * 64 + lane; // unit within plane
            const int sr = u >> 2;
            const int oc = (u & 3) ^ (sr & 3) ^ ((sr >> 2) & 3);
            gOff[t] = (unsigned)(((jj * BB + b) * 3 + sp) * XW_PLANE)
                    + (unsigned)((s0 + sr) * 512 + oc * 16);
        } else if (slot < 60) {
            const int sl = slot - 30;
            const int p  = sl >> 1;                // plane 0..14 = i*3+sp
            const int u  = (sl & 1) * 64 + lane;
            const int sr = u >> 2;                 // o-row within tile
            const int oc = (u & 3) ^ (sr & 3) ^ ((sr >> 2) & 3);
            gOff[t] = (unsigned)W2_OFF
                    + (unsigned)((p * CC + o0 + sr) * 512 + oc * 16);
        } else {
            const int sl = slot - 60;
            const int p  = sl >> 1;                // 0..9 = i*2+sp (sp in {0,1})
            const int i_ = p >> 1, sp = p & 1;
            const int u  = (sl & 1) * 64 + lane;
            const int sr = u >> 2;                 // o-row within tile
            const int oc = (u & 3) ^ (sr & 3) ^ ((sr >> 2) & 3);
            gOff[t] = (unsigned)AW_OFF
                    + (unsigned)(((i_ * 3 + sp) * CC + o0 + sr) * 512 + oc * 16);
        }
    }

    // ---- A-l frag per-lane base (k-minor planes; h/m come from LDS now) ----
    const unsigned vAW = (unsigned)AW_OFF + (unsigned)(o0 + ar) * 512u + (unsigned)qd * 16u;
    // X frag LDS byte offset (within plane, swizzled)
    const unsigned xb = (unsigned)(xr * 4 + (qd ^ (xr & 3) ^ ((xr >> 2) & 3))) * 16u;
    // W2/A frag LDS byte offset (within plane, swizzled; o-row = ar)
    const unsigned wb = (unsigned)(ar * 4 + (qd ^ (ar & 3) ^ ((ar >> 2) & 3))) * 16u;

    f32x4 accY[NI][NN];
    f32x4 accU[NI];
    #pragma unroll
    for (int ii = 0; ii < NI; ii++) {
        accU[ii] = (f32x4){0.f, 0.f, 0.f, 0.f};
        #pragma unroll
        for (int j = 0; j < NN; j++) accY[ii][j] = (f32x4){0.f, 0.f, 0.f, 0.f};
    }

    #pragma unroll 1
    for (int k0 = 0; k0 < CC; k0 += 32) {
        if (k0) __syncthreads();
        // X + W2 + A-hm staging DMA (swizzle carried in gaddr)
        #pragma unroll
        for (int t = 0; t < 20; t++) {
            GLD16(ws + gOff[t], SB + (sbase + t) * 1024);
            gOff[t] += 64;
        }
        // A-l frags for this chunk (global->reg; latency folds into the drain)
        short8 af[NI][3];
        #pragma unroll
        for (int ii = 0; ii < NI; ii++)
            af[ii][2] = *(const short8*)(ws + vAW
                + (unsigned)(((IB + ii) * 3 + 2) * AW_PLANE) + (unsigned)k0 * 2);
        __syncthreads();

        // A h/m frags from LDS (plane i*2+sp)
        #pragma unroll
        for (int ii = 0; ii < NI; ii++) {
            const unsigned char* ap = SB + 61440u + (unsigned)((IB + ii) * 2) * 2048u + wb;
            af[ii][0] = *(const short8*)(ap);
            af[ii][1] = *(const short8*)(ap + 2048);
        }

        // j-outer: X frags read once, shared across the i-set
        #pragma unroll
        for (int j = 0; j < NN; j++) {
            const unsigned char* xp = SB + (unsigned)(j * 3) * 2048u + xb;
            const short8 x0 = *(const short8*)(xp);
            const short8 x1 = *(const short8*)(xp + 2048);
            const short8 x2 = *(const short8*)(xp + 4096);
            #pragma unroll
            for (int ii = 0; ii < NI; ii++) {
                f32x4 c = accY[ii][j];
                c = MF(af[ii][0], x0, c);    // h*h
                c = MF(af[ii][0], x1, c);    // h*m
                c = MF(af[ii][1], x0, c);    // m*h
                c = MF(af[ii][0], x2, c);    // h*l
                c = MF(af[ii][2], x0, c);    // l*h   (m*m dropped: ~2^-16 rel)
                accY[ii][j] = c;
            }
            if (j >= IB && j < IB + NI) {        // compile-time on unroll index
                const int ui = j - IB;
                // W2 frags from LDS (plane i*3+sp with i == j here)
                const unsigned char* wp = SB + 30720u + (unsigned)(j * 3) * 2048u + wb;
                const short8 w0f = *(const short8*)(wp);
                const short8 w1f = *(const short8*)(wp + 2048);
                const short8 w2f = *(const short8*)(wp + 4096);
                f32x4 u = accU[ui];
                u = MF(w0f, x0, u);          // h*h
                u = MF(w0f, x1, u);          // h*m
                u = MF(w1f, x0, u);          // m*h
                u = MF(w0f, x2, u);          // h*l
                u = MF(w2f, x0, u);          // l*h   (m*m dropped)
                accU[ui] = u;
            }
        }
    }

    // ---------------- epilogue (C/D: col=lane&15, row=qd*4+reg) ----------------
    const int sg  = s0 + 16 * sh + m_;
    const int og0 = o0 + 16 * oh + 4 * qd;

    float xe[NN][4];
    #pragma unroll
    for (int j = 0; j < NN; j++) {
        const float* px = x + (size_t)((j * BB + b) * CC + og0) * SSP + sg;
        #pragma unroll
        for (int r = 0; r < 4; r++) xe[j][r] = px[r * SSP];
    }

    #pragma unroll
    for (int ii = 0; ii < NI; ii++) {
        const int i = IB + ii;
        #pragma unroll
        for (int r = 0; r < 4; r++) {
            const float uu = accU[ii][r] + bias[i * CC + og0 + r];
            float e[NN]; float mx = 0.f;
            #pragma unroll
            for (int j = 0; j < NN; j++) {
                float d = fabsf(xe[j][r] - (accY[ii][j][r] + uu));
                d = (d > THRESHV) ? d : 0.f;
                e[j] = d; mx = fmaxf(mx, d);
            }
            float sum = 0.f, hv = 0.f;
            #pragma unroll
            for (int j = 0; j < NN; j++) {
                const float p = __expf(e[j] - mx);
                sum += p; hv += p * xe[j][r];
            }
            out[(size_t)((i * BB + b) * CC + og0 + r) * SSP + sg] = hv / sum;
        }
    }
}

// ================= fallback (R2 kernel, self-splitting; known-good) ==========
static __device__ __forceinline__ void st4(unsigned short* p, unsigned short a,
                                           unsigned short b, unsigned short c, unsigned short d) {
    ushort4 v; v.x = a; v.y = b; v.z = c; v.w = d;
    *(ushort4*)p = v;
}
#define XB 15360
__global__ __launch_bounds__(512, 2)
void fub_mfma(const float* __restrict__ x, const float* __restrict__ w,
              const float* __restrict__ bias, float* __restrict__ out)
{
    __shared__ unsigned short S[30720];
    const int tid = threadIdx.x;
    const int b = blockIdx.z, o0 = blockIdx.y * 32, s0 = blockIdx.x * 32;
    const int lane = tid & 63, wv = tid >> 6;
    const int q = wv & 3, oh = q >> 1, sh = q & 1, iset = wv >> 2, qd = lane >> 4;
    const int sub = tid >> 8, t = tid & 255;
    const int wo = t >> 3, wkg = t & 7, xs = t & 31, xkq = t >> 5;
    const int wbase = wo * 32 + (((wkg >> 1) ^ ((wo >> 1) & 3)) << 3) + ((wkg & 1) << 2);
    const int xbase = xs * 32 + (((xkq >> 1) ^ ((xs >> 1) & 3)) << 3) + ((xkq & 1) << 2);
    const int ar = 16 * oh + (lane & 15), xr = 16 * sh + (lane & 15);
    const int asw8 = ((qd ^ ((ar >> 1) & 3)) << 3), xsw8 = ((qd ^ ((xr >> 1) & 3)) << 3);
    const int arow32 = ar * 32, xrow32 = xr * 32;
    f32x4 accY[3][5]; f32x4 accU[3];
    #pragma unroll
    for (int ii = 0; ii < 3; ii++) {
        accU[ii] = (f32x4){0.f, 0.f, 0.f, 0.f};
        #pragma unroll
        for (int j = 0; j < NN; j++) accY[ii][j] = (f32x4){0.f, 0.f, 0.f, 0.f};
    }
    float w2sav[3][4];
    #pragma unroll 1
    for (int k0 = 0; k0 < CC; k0 += 32) {
        if (k0) __syncthreads();
        #pragma unroll
        for (int rep = 0; rep < 3; rep++) {
            const int i = rep * 2 + sub;
            if (i < NN) {
                const float* gw = w + (size_t)(i * CC + o0 + wo) * (2 * CC) + k0 + wkg * 4;
                const float4 w1 = *(const float4*)gw;
                const float4 w2 = *(const float4*)(gw + CC);
                w2sav[rep][0] = w2.x; w2sav[rep][1] = w2.y; w2sav[rep][2] = w2.z; w2sav[rep][3] = w2.w;
                float av[4] = {w1.x + w2.x, w1.y + w2.y, w1.z + w2.z, w1.w + w2.w};
                unsigned short h[4], m[4], l[4];
                #pragma unroll
                for (int r = 0; r < 4; r++) split3(av[r], h[r], m[r], l[r]);
                unsigned short* p = &S[i * 3 * 1024 + wbase];
                st4(p, h[0], h[1], h[2], h[3]); st4(p + 1024, m[0], m[1], m[2], m[3]); st4(p + 2048, l[0], l[1], l[2], l[3]);
            }
        }
        #pragma unroll
        for (int rep = 0; rep < 3; rep++) {
            const int j = rep * 2 + sub;
            if (j < NN) {
                const float* gx = x + (size_t)((j * BB + b) * CC + k0 + xkq * 4) * SSP + s0 + xs;
                float v[4] = {gx[0], gx[SSP], gx[2 * SSP], gx[3 * SSP]};
                unsigned short h[4], m[4], l[4];
                #pragma unroll
                for (int r = 0; r < 4; r++) split3(v[r], h[r], m[r], l[r]);
                unsigned short* p = &S[XB + j * 3 * 1024 + xbase];
                st4(p, h[0], h[1], h[2], h[3]); st4(p + 1024, m[0], m[1], m[2], m[3]); st4(p + 2048, l[0], l[1], l[2], l[3]);
            }
        }
        __syncthreads();
        short8 xf[NN][3];
        #pragma unroll
        for (int j = 0; j < NN; j++)
            #pragma unroll
            for (int sp = 0; sp < 3; sp++)
                xf[j][sp] = *(const short8*)&S[XB + (j * 3 + sp) * 1024 + xrow32 + xsw8];
#define YPL(IB_, NI_)                                                           \
        {                                                                       \
            _Pragma("unroll")                                                   \
            for (int ii = 0; ii < NI_; ii++) {                                  \
                const int i = IB_ + ii;                                         \
                const unsigned short* ap = &S[i * 3 * 1024 + arow32 + asw8];    \
                const short8 ah = *(const short8*)(ap);                         \
                const short8 am = *(const short8*)(ap + 1024);                  \
                const short8 al = *(const short8*)(ap + 2048);                  \
                _Pragma("unroll")                                               \
                for (int j = 0; j < NN; j++) {                                  \
                    f32x4 c = accY[ii][j];                                      \
                    c = MF(ah, xf[j][0], c); c = MF(ah, xf[j][1], c);           \
                    c = MF(am, xf[j][0], c); c = MF(am, xf[j][1], c);           \
                    c = MF(ah, xf[j][2], c); c = MF(al, xf[j][0], c);           \
                    accY[ii][j] = c;                                            \
                }                                                               \
            }                                                                   \
        }
        if (iset == 0) { YPL(0, 2) } else { YPL(2, 3) }
        __syncthreads();
        #pragma unroll
        for (int rep = 0; rep < 3; rep++) {
            const int i = rep * 2 + sub;
            if (i < NN) {
                unsigned short h[4], m[4], l[4];
                #pragma unroll
                for (int r = 0; r < 4; r++) split3(w2sav[rep][r], h[r], m[r], l[r]);
                unsigned short* p = &S[i * 3 * 1024 + wbase];
                st4(p, h[0], h[1], h[2], h[3]); st4(p + 1024, m[0], m[1], m[2], m[3]); st4(p + 2048, l[0], l[1], l[2], l[3]);
            }
        }
        __syncthreads();
#define UPL(IB_, NI_)                                                           \
        {                                                                       \
            _Pragma("unroll")                                                   \
            for (int ii = 0; ii < NI_; ii++) {                                  \
                const int i = IB_ + ii;                                         \
                const unsigned short* wp = &S[i * 3 * 1024 + arow32 + asw8];    \
                const short8 wh = *(const short8*)(wp);                         \
                const short8 wm = *(const short8*)(wp + 1024);                  \
                const short8 wl = *(const short8*)(wp + 2048);                  \
                f32x4 u = accU[ii];                                             \
                u = MF(wh, xf[i][0], u); u = MF(wh, xf[i][1], u);               \
                u = MF(wm, xf[i][0], u); u = MF(wm, xf[i][1], u);               \
                u = MF(wh, xf[i][2], u); u = MF(wl, xf[i][0], u);               \
                accU[ii] = u;                                                   \
            }                                                                   \
        }
        if (iset == 0) { UPL(0, 2) } else { UPL(2, 3) }
    }
    const int sg = s0 + 16 * sh + (lane & 15);
    const int og0 = o0 + 16 * oh + 4 * qd;
    float xe[NN][4];
    #pragma unroll
    for (int j = 0; j < NN; j++) {
        const float* px = x + (size_t)((j * BB + b) * CC + og0) * SSP + sg;
        #pragma unroll
        for (int r = 0; r < 4; r++) xe[j][r] = px[r * SSP];
    }
#define EPI(IB_, NI_)                                                           \
    {                                                                           \
        _Pragma("unroll")                                                       \
        for (int ii = 0; ii < NI_; ii++) {                                      \
            const int i = IB_ + ii;                                             \
            _Pragma("unroll")                                                   \
            for (int r = 0; r < 4; r++) {                                       \
                const float uu = accU[ii][r] + bias[i * CC + og0 + r];          \
                float e[NN]; float mx = 0.f;                                    \
                _Pragma("unroll")                                               \
                for (int j = 0; j < NN; j++) {                                  \
                    float d = fabsf(xe[j][r] - (accY[ii][j][r] + uu));          \
                    d = (d > THRESHV) ? d : 0.f;                                \
                    e[j] = d; mx = fmaxf(mx, d);                                \
                }                                                               \
                float sum = 0.f, hv = 0.f;                                      \
                _Pragma("unroll")                                               \
                for (int j = 0; j < NN; j++) {                                  \
                    const float p = __expf(e[j] - mx);                          \
                    sum += p; hv += p * xe[j][r];                               \
                }                                                               \
                out[(size_t)((i * BB + b) * CC + og0 + r) * SSP + sg] = hv / sum; \
            }                                                                   \
        }                                                                       \
    }
    if (iset == 0) { EPI(0, 2) } else { EPI(2, 3) }
}

extern "C" void kernel_launch(void* const* d_in, const int* in_sizes, int n_in,
                              void* d_out, int out_size, void* d_ws, size_t ws_size,
                              hipStream_t stream) {
    const float* x      = (const float*)d_in[0];
    const float* conv_w = (const float*)d_in[1];
    const float* conv_b = (const float*)d_in[2];
    float* out = (float*)d_out;

    if (ws_size >= WS_NEED) {
        unsigned char* ws = (unsigned char*)d_ws;
        prep_all<<<2720, 256, 0, stream>>>(x, conv_w, ws);
        dim3 grid(SSP / 32, CC / 32, BB);   // 2048 blocks, all 5 i fused
        fub_main<0, 5><<<grid, 256, 0, stream>>>(x, conv_b, ws, out);
    } else {
        fub_mfma<<<dim3(SSP / 32, CC / 32, BB), 512, 0, stream>>>(x, conv_w, conv_b, out);
    }
}